// Round 9
// baseline (208.179 us; speedup 1.0000x reference)
//
#include <hip/hip_runtime.h>

typedef unsigned short u16;
typedef unsigned int u32;
typedef __attribute__((ext_vector_type(8))) short bf16x8;
typedef __attribute__((ext_vector_type(4))) float f32x4;
typedef __attribute__((ext_vector_type(4))) u32 u32x4;
typedef __attribute__((ext_vector_type(2))) u32 u32x2;

__device__ __forceinline__ u16 f2bf(float f) {
  u32 u = __builtin_bit_cast(u32, f);
  return (u16)((u + 0x7FFFu + ((u >> 16) & 1u)) >> 16);
}
__device__ __forceinline__ float bf2f(u16 b) {
  return __builtin_bit_cast(float, (u32)b << 16);
}

// v_cvt_pk_bf16_f32 = RNE, bitwise-identical to f2bf for finite inputs
// (proven: r6 fused gemm1 kept absmax exactly 0.001953125).
__device__ __forceinline__ u32 cvtpk(float lo, float hi) {
  u32 r;
  asm("v_cvt_pk_bf16_f32 %0, %1, %2" : "=v"(r) : "v"(lo), "v"(hi));
  return r;
}

__device__ __forceinline__ float fexp2(float x) {
#if __has_builtin(__builtin_amdgcn_exp2f)
  return __builtin_amdgcn_exp2f(x);
#else
  return __expf(x * 0.6931471805599453f);
#endif
}

__device__ __forceinline__ void lds_async16(const void* g, void* l) {
  auto gp = reinterpret_cast<const __attribute__((address_space(1))) u32*>(
      reinterpret_cast<uintptr_t>(g));
  auto lp = reinterpret_cast<__attribute__((address_space(3))) u32*>(
      reinterpret_cast<uintptr_t>(l));
  __builtin_amdgcn_global_load_lds(gp, lp, 16, 0, 0);
}

// two small weight converts in one launch
__global__ void cvt2_kernel(const float* __restrict__ a, const float* __restrict__ b,
                            u16* __restrict__ oa, u16* __restrict__ ob, int na4, int nb4) {
  int i = blockIdx.x * 256 + threadIdx.x;
  const float* src;
  u16* dst;
  int idx;
  if (i < na4) {
    src = a; dst = oa; idx = i;
  } else {
    idx = i - na4;
    if (idx >= nb4) return;
    src = b; dst = ob;
  }
  f32x4 v = *(const f32x4*)(src + (size_t)idx * 4);
  u32x2 o;
  o[0] = (u32)f2bf(v[0]) | ((u32)f2bf(v[1]) << 16);
  o[1] = (u32)f2bf(v[2]) | ((u32)f2bf(v[3]) << 16);
  *(u32x2*)(dst + (size_t)idx * 4) = o;
}

// ---------------- GEMM (bf16 A): C[m][n] = sum_k A[m][k]*B[n][k] + bias[n] ----
// EXACT proven version (pre-r6). Used for gemm2 only now.
// Operand swap mfma(bfr, af) produced absmax 1.01 — reverted permanently.
// Do NOT swap the mfma operand order here.
template <bool OUT_BF16>
__global__ __launch_bounds__(256) void gemm_bt_kernel(
    const u16* __restrict__ A, const u16* __restrict__ B,
    const float* __restrict__ bias, void* __restrict__ C,
    int M, int N, int K) {
  __shared__ u16 sA[128 * 32];
  __shared__ u16 sB[128 * 32];
  const int tid = threadIdx.x;
  const int m0 = blockIdx.x * 128;
  const int n0 = blockIdx.y * 128;
  const int w = tid >> 6;
  const int lane = tid & 63;
  const int wr = (w >> 1) * 64;
  const int wc = (w & 1) * 64;
  const int lm = lane & 15;
  const int lk = (lane >> 4) * 8;

  f32x4 acc[4][4] = {};

  const int srow = tid >> 2;
  const int ssub = (tid & 3) * 8;
  const u16* Ag = A + (size_t)(m0 + srow) * K + ssub;
  const u16* Bg = B + (size_t)(n0 + srow) * K + ssub;
  const size_t rstep = (size_t)64 * K;

  for (int k0 = 0; k0 < K; k0 += 32) {
    __syncthreads();
    lds_async16(Ag + k0, &sA[tid * 8]);
    lds_async16(Ag + rstep + k0, &sA[2048 + tid * 8]);
    lds_async16(Bg + k0, &sB[tid * 8]);
    lds_async16(Bg + rstep + k0, &sB[2048 + tid * 8]);
    __syncthreads();
    bf16x8 af[4], bfr[4];
#pragma unroll
    for (int i = 0; i < 4; ++i)
      af[i] = *(const bf16x8*)&sA[(wr + i * 16 + lm) * 32 + lk];
#pragma unroll
    for (int j = 0; j < 4; ++j)
      bfr[j] = *(const bf16x8*)&sB[(wc + j * 16 + lm) * 32 + lk];
#pragma unroll
    for (int i = 0; i < 4; ++i)
#pragma unroll
      for (int j = 0; j < 4; ++j)
        acc[i][j] = __builtin_amdgcn_mfma_f32_16x16x32_bf16(af[i], bfr[j], acc[i][j], 0, 0, 0);
  }

  const int r0 = (lane >> 4) * 4;
#pragma unroll
  for (int j = 0; j < 4; ++j) {
    const int n = n0 + wc + j * 16 + lm;
    const float bv = bias[n];
#pragma unroll
    for (int i = 0; i < 4; ++i) {
#pragma unroll
      for (int r = 0; r < 4; ++r) {
        const int m = m0 + wr + i * 16 + r0 + r;
        float v = acc[i][j][r] + bv;
        if (OUT_BF16)
          ((u16*)C)[(size_t)m * N + n] = f2bf(v);
        else
          ((float*)C)[(size_t)m * N + n] = v;
      }
    }
  }
}

// ---------------- GEMM1 (f32 A direct): qkv = x @ w_in^T + b_in, bf16 out ----
// Round-7 restructure of the latency-bound gemm1 (was 45-47us, MfmaUtil 10%,
// everything-low counters):
//  - A fragments loaded DIRECT from f32 global (rows m0+wr+i*16+lm, cols
//    k0+lg*8..+7 = 2 x f32x4) and converted in regs via cvtpk (RNE == f2bf,
//    bitwise identical to the staged path). Deletes sA, A ds_write/ds_read,
//    and the A-convert from the barrier-critical section. x re-reads are
//    L2/L3-resident (34.6MB << 256MB L3).
//  - sB double-buffered (2 x 8KB = same 16KB LDS): ONE barrier per k-step
//    (was 2); next B-tile's global_load_lds stays in flight across the MFMA
//    body. Order per iter: barrier (drains buf[ks] stage) -> issue stage
//    buf[ks^1] -> A frags + bfr reads -> 16 MFMA. WAR on buf[ks^1] is safe:
//    its readers ran before the barrier.
//  - launch_bounds(256,4) pins VGPR <= 128 (current gemm is already in the
//    4-waves/SIMD band at 84 VGPR; don't let f32 staging regs cross a cliff).
// mfma operand order / fragment defs / epilogue copied verbatim from the
// proven kernel. Revert criterion: gemm1 >= 45us or absmax change.
// (r7/r8 bench attempts died in container bring-up — no timing dict, same
// signature as r1's transient; kernel audited for OOB/deadlock: clean.)
__global__ __launch_bounds__(256, 4) void gemm_a32_kernel(
    const float* __restrict__ A, const u16* __restrict__ B,
    const float* __restrict__ bias, u16* __restrict__ C,
    int M, int N, int K) {
  __shared__ u16 sB[2][128 * 32];
  const int tid = threadIdx.x;
  const int m0 = blockIdx.x * 128;
  const int n0 = blockIdx.y * 128;
  const int w = tid >> 6;
  const int lane = tid & 63;
  const int wr = (w >> 1) * 64;
  const int wc = (w & 1) * 64;
  const int lm = lane & 15;
  const int lk = (lane >> 4) * 8;

  f32x4 acc[4][4] = {};

  const int srow = tid >> 2;
  const int ssub = (tid & 3) * 8;
  const u16* Bg = B + (size_t)(n0 + srow) * K + ssub;
  const size_t rstep = (size_t)64 * K;

  // A fragment base: row m0+wr+lm (+16 per i), col lk
  const float* Af = A + (size_t)(m0 + wr + lm) * K + lk;
  const size_t astep = (size_t)16 * K;

  // prologue: stage B tile 0 into buf 0
  lds_async16(Bg, &sB[0][tid * 8]);
  lds_async16(Bg + rstep, &sB[0][2048 + tid * 8]);

  const int nt = K >> 5;
  for (int ks = 0; ks < nt; ++ks) {
    const int buf = ks & 1;
    __syncthreads();  // buf[ks] staged; prev iter's reads of buf[ks^1] done
    if (ks + 1 < nt) {
      const int k1 = (ks + 1) * 32;
      lds_async16(Bg + k1, &sB[buf ^ 1][tid * 8]);
      lds_async16(Bg + rstep + k1, &sB[buf ^ 1][2048 + tid * 8]);
    }
    const int k0 = ks * 32;
    bf16x8 af[4];
#pragma unroll
    for (int i = 0; i < 4; ++i) {
      const float* ap = Af + (size_t)i * astep + k0;
      f32x4 lo = *(const f32x4*)ap;
      f32x4 hi = *(const f32x4*)(ap + 4);
      u32x4 pw;
      pw[0] = cvtpk(lo[0], lo[1]);
      pw[1] = cvtpk(lo[2], lo[3]);
      pw[2] = cvtpk(hi[0], hi[1]);
      pw[3] = cvtpk(hi[2], hi[3]);
      af[i] = __builtin_bit_cast(bf16x8, pw);
    }
    bf16x8 bfr[4];
#pragma unroll
    for (int j = 0; j < 4; ++j)
      bfr[j] = *(const bf16x8*)&sB[buf][(wc + j * 16 + lm) * 32 + lk];
#pragma unroll
    for (int i = 0; i < 4; ++i)
#pragma unroll
      for (int j = 0; j < 4; ++j)
        acc[i][j] = __builtin_amdgcn_mfma_f32_16x16x32_bf16(af[i], bfr[j], acc[i][j], 0, 0, 0);
  }

  const int r0 = (lane >> 4) * 4;
#pragma unroll
  for (int j = 0; j < 4; ++j) {
    const int n = n0 + wc + j * 16 + lm;
    const float bv = bias[n];
#pragma unroll
    for (int i = 0; i < 4; ++i) {
#pragma unroll
      for (int r = 0; r < 4; ++r) {
        const int m = m0 + wr + i * 16 + r0 + r;
        C[(size_t)m * N + n] = f2bf(acc[i][j][r] + bv);
      }
    }
  }
}

// ---------------- fused per-(block,head) attention ----------------
// ROUND-2 EXACT SOURCE (proven 44.5-44.9us, VGPR 64). Do not "improve"
// without a within-session A/B.
// LEDGER (measured):
//  r2 44.9us: sVt col XOR-swizzle; cvt_pk packing; denominator via
//    mfma(P, ones); 1-deep K prefetch; setprio; single sP + WAR fence.
//  r3 48.0us REGRESSED: sP hf-dbuf + V-reg-prefetch -> VGPR 68 crossed the
//    64-VGPR allocation cliff (8->7 waves/SIMD), occ 31->24%.
//  r4 48.0us: sP-XOR changed conflict count by exactly 0 -> conflicts are
//    NOT sP; V-prefetch's +4 VGPR was the whole r3 regression.
//    LESSON: stay at VGPR <= 64.
//  r5 FAILED (absmax 0.19): K-row re-tiling to keep PV A-fragment in regs.
//    OPEN MYSTERY — do not retry without disasm evidence.
// launch_bounds(256,2): (256,4) spilled catastrophically. `#pragma unroll 1`
// on the ch loop is load-bearing: full unroll hoists all kf loads and spills.
// The asm memory fence pins the P-tile read -> overwrite (WAR) order.
__global__ __launch_bounds__(256, 2) void attn_kernel(const u16* __restrict__ qkv,
                                                      u16* __restrict__ o_ws) {
  __shared__ u16 sVt[32 * 264];   // V transposed, stride 264 u16, cols XOR-swizzled
  __shared__ u16 sP[4 * 32 * 40]; // per-wave P half-tile: 32 rows x 40 u16

  const int bid = blockIdx.x;
  const int n = bid >> 3;
  const int h = bid & 7;
  const int rowbase = (n >> 5) * 4224 + (n & 31) * 128;
  const int tid = threadIdx.x;
  const int w = tid >> 6;
  const int lane = tid & 63;
  const int lm = lane & 15;
  const int lg = lane >> 4;

  // stage V transposed for this head: V[j][d] -> sVt[d*264 + (j ^ ((d>>3)<<4))]
#pragma unroll
  for (int it = 0; it < 4; ++it) {
    int c = it * 256 + tid;
    int row = c >> 2;
    int sub = (c & 3) * 8;
    int rsw = row ^ ((sub >> 3) << 4);   // swizzled column; (d>>3) is sub>>3 for all 8 d
    const u16* gv = qkv + (size_t)(rowbase + row) * 768 + 512 + h * 32 + sub;
    u32x4 vv = *(const u32x4*)gv;
#pragma unroll
    for (int q = 0; q < 4; ++q) {
      sVt[(sub + 2 * q) * 264 + rsw] = (u16)(vv[q] & 0xFFFFu);
      sVt[(sub + 2 * q + 1) * 264 + rsw] = (u16)(vv[q] >> 16);
    }
  }

  // Q fragments straight from global (wave-private rows; 16 rows x 64B contiguous)
  bf16x8 qf[4];
#pragma unroll
  for (int rt = 0; rt < 4; ++rt) {
    int row = rowbase + w * 64 + rt * 16 + lm;
    qf[rt] = *(const bf16x8*)(qkv + (size_t)row * 768 + h * 32 + lg * 8);
  }

  const u16* kbase = qkv + (size_t)(rowbase + lm) * 768 + 256 + h * 32 + lg * 8;

  // prime K prefetch for ch=0 (overlaps the staging barrier)
  bf16x8 kfc[2];
#pragma unroll
  for (int ct = 0; ct < 2; ++ct)
    kfc[ct] = *(const bf16x8*)(kbase + (size_t)(ct * 16) * 768);

  __syncthreads();

  f32x4 oacc[4][2] = {};
  f32x4 lacc[4] = {};   // softmax denominators via mfma(P, ones)
  u16* myP = sP + w * (32 * 40);
  const float C1 = 0.25500035370494726f; // scale * log2(e)
  const float C2 = 1.4426950408889634f;  // log2(e)
  const int jq = lg * 4;
  const int D0w = w * 64;
  const bf16x8 onesb = {(short)0x3F80, (short)0x3F80, (short)0x3F80, (short)0x3F80,
                        (short)0x3F80, (short)0x3F80, (short)0x3F80, (short)0x3F80};

#pragma unroll 1
  for (int ch = 0; ch < 8; ++ch) {
    // prefetch next chunk's K fragments (clamped; last iter loads are dead)
    const int chn = (ch < 7) ? ch + 1 : 7;
    bf16x8 kfn[2], vf[2];
#pragma unroll
    for (int ct = 0; ct < 2; ++ct)
      kfn[ct] = *(const bf16x8*)(kbase + (size_t)(chn * 32 + ct * 16) * 768);
#pragma unroll
    for (int ctd = 0; ctd < 2; ++ctd) {
      int d = ctd * 16 + lm;
      vf[ctd] = *(const bf16x8*)&sVt[d * 264 + ((ch * 32 + lg * 8) ^ ((d >> 3) << 4))];
    }

#pragma unroll
    for (int hf = 0; hf < 2; ++hf) {
#pragma unroll
      for (int ct = 0; ct < 2; ++ct) {
#pragma unroll
        for (int rl = 0; rl < 2; ++rl) {
          const int rt = hf * 2 + rl;
          f32x4 s = __builtin_amdgcn_mfma_f32_16x16x32_bf16(kfc[ct], qf[rt], f32x4{0.f, 0.f, 0.f, 0.f}, 0, 0, 0);
          const int D0 = D0w + rt * 16 - (ch * 32 + ct * 16); // wave-uniform
          float p0, p1, p2, p3;
          if (D0 >= 16 && D0 <= 112) {        // fully in-band: +1 bias
            p0 = fexp2(__builtin_fmaf(s[0], C1, C2));
            p1 = fexp2(__builtin_fmaf(s[1], C1, C2));
            p2 = fexp2(__builtin_fmaf(s[2], C1, C2));
            p3 = fexp2(__builtin_fmaf(s[3], C1, C2));
          } else if (D0 == 0) {               // diagonal: in-band iff lm >= jq+r
            p0 = fexp2(__builtin_fmaf(s[0], C1, (lm >= jq + 0) ? C2 : 0.0f));
            p1 = fexp2(__builtin_fmaf(s[1], C1, (lm >= jq + 1) ? C2 : 0.0f));
            p2 = fexp2(__builtin_fmaf(s[2], C1, (lm >= jq + 2) ? C2 : 0.0f));
            p3 = fexp2(__builtin_fmaf(s[3], C1, (lm >= jq + 3) ? C2 : 0.0f));
          } else if (D0 == 128) {             // far edge: in-band iff lm < jq+r
            p0 = fexp2(__builtin_fmaf(s[0], C1, (lm < jq + 0) ? C2 : 0.0f));
            p1 = fexp2(__builtin_fmaf(s[1], C1, (lm < jq + 1) ? C2 : 0.0f));
            p2 = fexp2(__builtin_fmaf(s[2], C1, (lm < jq + 2) ? C2 : 0.0f));
            p3 = fexp2(__builtin_fmaf(s[3], C1, (lm < jq + 3) ? C2 : 0.0f));
          } else {                            // fully out of band: no bias
            p0 = fexp2(s[0] * C1);
            p1 = fexp2(s[1] * C1);
            p2 = fexp2(s[2] * C1);
            p3 = fexp2(s[3] * C1);
          }
          u32 a0, a1;
          asm("v_cvt_pk_bf16_f32 %0, %1, %2" : "=v"(a0) : "v"(p0), "v"(p1));
          asm("v_cvt_pk_bf16_f32 %0, %1, %2" : "=v"(a1) : "v"(p2), "v"(p3));
          u32x2 pk;
          pk[0] = a0;
          pk[1] = a1;
          *(u32x2*)&myP[(rl * 16 + lm) * 40 + ct * 16 + jq] = pk;
        }
      }
      // O(half) += P(half) * Vc ; lsum(half) += P(half) . 1  (wave-private P)
      bf16x8 pf[2];
#pragma unroll
      for (int rl = 0; rl < 2; ++rl)
        pf[rl] = *(const bf16x8*)&myP[(rl * 16 + lm) * 40 + lg * 8];
      // pin WAR order: these reads must precede the next half's overwrites
      __asm__ __volatile__("" ::: "memory");
      __builtin_amdgcn_s_setprio(1);
#pragma unroll
      for (int rl = 0; rl < 2; ++rl) {
        lacc[hf * 2 + rl] =
            __builtin_amdgcn_mfma_f32_16x16x32_bf16(pf[rl], onesb, lacc[hf * 2 + rl], 0, 0, 0);
#pragma unroll
        for (int ctd = 0; ctd < 2; ++ctd)
          oacc[hf * 2 + rl][ctd] =
              __builtin_amdgcn_mfma_f32_16x16x32_bf16(pf[rl], vf[ctd], oacc[hf * 2 + rl][ctd], 0, 0, 0);
      }
      __builtin_amdgcn_s_setprio(0);
    }
    kfc[0] = kfn[0];
    kfc[1] = kfn[1];
  }

  // normalize + store; lacc[rt][r] holds the full denominator for row
  // i = rt*16 + lg*4 + r (C/D layout row = lg*4+r), exactly the epilogue row.
#pragma unroll
  for (int rt = 0; rt < 4; ++rt) {
#pragma unroll
    for (int r = 0; r < 4; ++r) {
      float inv = 1.0f / lacc[rt][r];
      int i_g = w * 64 + rt * 16 + jq + r;
#pragma unroll
      for (int ctd = 0; ctd < 2; ++ctd) {
        float v = oacc[rt][ctd][r] * inv;
        u32 u = __builtin_bit_cast(u32, v) + 0x8000u;
        o_ws[((size_t)(n * 256 + i_g)) * 256 + h * 32 + ctd * 16 + lm] = (u16)(u >> 16);
      }
    }
  }
}

// ---------------- overlap-add combine: oc[t] = sum(covering o_ws)/cnt ----------------
__global__ void combine_kernel(const u16* __restrict__ o_ws, u16* __restrict__ oc) {
  int gid = blockIdx.x * 256 + threadIdx.x;
  int m = gid >> 5;             // global row (bc*4224 + t)
  int f0 = (gid & 31) << 3;     // 8 features per thread
  int bc = m / 4224;
  int t = m - bc * 4224;
  int i0 = t >> 7;
  float a[8] = {0.f, 0.f, 0.f, 0.f, 0.f, 0.f, 0.f, 0.f};
  if (i0 <= 31) {
    const u16* p = o_ws + ((size_t)((bc * 32 + i0) * 256 + (t - (i0 << 7)))) * 256 + f0;
    u32x4 v = *(const u32x4*)p;
#pragma unroll
    for (int q = 0; q < 4; ++q) {
      a[2 * q] += bf2f((u16)(v[q] & 0xFFFFu));
      a[2 * q + 1] += bf2f((u16)(v[q] >> 16));
    }
  }
  if (i0 >= 1) {
    int i1 = i0 - 1;
    const u16* p = o_ws + ((size_t)((bc * 32 + i1) * 256 + (t - (i1 << 7)))) * 256 + f0;
    u32x4 v = *(const u32x4*)p;
#pragma unroll
    for (int q = 0; q < 4; ++q) {
      a[2 * q] += bf2f((u16)(v[q] & 0xFFFFu));
      a[2 * q + 1] += bf2f((u16)(v[q] >> 16));
    }
  }
  float sc = (i0 >= 1 && i0 <= 31) ? 0.5f : 1.0f;
  u32x2 o;
  o[0] = (u32)f2bf(a[0] * sc) | ((u32)f2bf(a[1] * sc) << 16);
  o[1] = (u32)f2bf(a[2] * sc) | ((u32)f2bf(a[3] * sc) << 16);
  u32x2 o2;
  o2[0] = (u32)f2bf(a[4] * sc) | ((u32)f2bf(a[5] * sc) << 16);
  o2[1] = (u32)f2bf(a[6] * sc) | ((u32)f2bf(a[7] * sc) << 16);
  u16* dst = oc + (size_t)m * 256 + f0;
  *(u32x2*)dst = o;
  *(u32x2*)(dst + 4) = o2;
}

extern "C" void kernel_launch(void* const* d_in, const int* in_sizes, int n_in,
                              void* d_out, int out_size, void* d_ws, size_t ws_size,
                              hipStream_t stream) {
  const float* x = (const float*)d_in[0];
  const float* w_in = (const float*)d_in[1];
  const float* b_in = (const float*)d_in[2];
  const float* w_out = (const float*)d_in[3];
  const float* b_out = (const float*)d_in[4];
  float* y = (float*)d_out;
  char* ws = (char*)d_ws;

  // workspace layout (bytes)
  u16* qkv = (u16*)(ws);                   // 33792*768*2   = 51,904,512
  u16* xbf = (u16*)(ws + 51904512);        // 33792*256*2   = 17,301,504 (oc only)
  u16* ows = (u16*)(ws + 69206016);        // 256*256*256*2 = 33,554,432
  u16* winb = (u16*)(ws + 102760448);      // 768*256*2     = 393,216
  u16* woutb = (u16*)(ws + 103153664);     // 256*256*2     = 131,072  (end 103,284,736)

  cvt2_kernel<<<256, 256, 0, stream>>>(w_in, w_out, winb, woutb, 49152, 16384);

  // qkv = x @ w_in^T + b_in — A direct from f32, sB double-buffered
  gemm_a32_kernel<<<dim3(264, 6), 256, 0, stream>>>(x, winb, b_in, qkv, 33792, 768, 256);

  // per-(block, head) attention
  attn_kernel<<<2048, 256, 0, stream>>>(qkv, ows);

  // overlap-add + count division (commutes with the linear w_out projection)
  combine_kernel<<<4224, 256, 0, stream>>>(ows, xbf);

  // y = oc @ w_out^T + b_out
  gemm_bt_kernel<false><<<dim3(264, 2), 256, 0, stream>>>(xbf, woutb, b_out, y, 33792, 256, 256);
}

// Round 10
// 180.379 us; speedup vs baseline: 1.1541x; 1.1541x over previous
//
#include <hip/hip_runtime.h>

typedef unsigned short u16;
typedef unsigned int u32;
typedef __attribute__((ext_vector_type(8))) short bf16x8;
typedef __attribute__((ext_vector_type(4))) float f32x4;
typedef __attribute__((ext_vector_type(4))) u32 u32x4;
typedef __attribute__((ext_vector_type(2))) u32 u32x2;

__device__ __forceinline__ u16 f2bf(float f) {
  u32 u = __builtin_bit_cast(u32, f);
  return (u16)((u + 0x7FFFu + ((u >> 16) & 1u)) >> 16);
}
__device__ __forceinline__ float bf2f(u16 b) {
  return __builtin_bit_cast(float, (u32)b << 16);
}

// v_cvt_pk_bf16_f32 = RNE, bitwise-identical to f2bf for finite inputs
// (proven: r6 fused gemm1 kept absmax exactly 0.001953125).
__device__ __forceinline__ u32 cvtpk(float lo, float hi) {
  u32 r;
  asm("v_cvt_pk_bf16_f32 %0, %1, %2" : "=v"(r) : "v"(lo), "v"(hi));
  return r;
}

__device__ __forceinline__ float fexp2(float x) {
#if __has_builtin(__builtin_amdgcn_exp2f)
  return __builtin_amdgcn_exp2f(x);
#else
  return __expf(x * 0.6931471805599453f);
#endif
}

__device__ __forceinline__ void lds_async16(const void* g, void* l) {
  auto gp = reinterpret_cast<const __attribute__((address_space(1))) u32*>(
      reinterpret_cast<uintptr_t>(g));
  auto lp = reinterpret_cast<__attribute__((address_space(3))) u32*>(
      reinterpret_cast<uintptr_t>(l));
  __builtin_amdgcn_global_load_lds(gp, lp, 16, 0, 0);
}

// two small weight converts in one launch
__global__ void cvt2_kernel(const float* __restrict__ a, const float* __restrict__ b,
                            u16* __restrict__ oa, u16* __restrict__ ob, int na4, int nb4) {
  int i = blockIdx.x * 256 + threadIdx.x;
  const float* src;
  u16* dst;
  int idx;
  if (i < na4) {
    src = a; dst = oa; idx = i;
  } else {
    idx = i - na4;
    if (idx >= nb4) return;
    src = b; dst = ob;
  }
  f32x4 v = *(const f32x4*)(src + (size_t)idx * 4);
  u32x2 o;
  o[0] = (u32)f2bf(v[0]) | ((u32)f2bf(v[1]) << 16);
  o[1] = (u32)f2bf(v[2]) | ((u32)f2bf(v[3]) << 16);
  *(u32x2*)(dst + (size_t)idx * 4) = o;
}

// ---------------- GEMM: C[m][n] = sum_k A[m][k]*B[n][k] + bias[n] ----------------
// EXACT r6 version (proven passing, total 179.6us). gemm1 uses A_F32=true:
// A staged from f32 global via reg-load (issued BEFORE the WAR barrier, so
// HBM latency overlaps the previous k-step's MFMAs) + cvtpk + ds_write.
// Operand swap mfma(bfr, af) produced absmax 1.01 — reverted permanently.
// Do NOT swap the mfma operand order here.
// LEDGER r9 (measured, FAILED): A-fragments DIRECT from global f32 per
// k-step (gemm_a32_kernel, sB dbuf, 1 barrier) = 73.2us vs 46 — MfmaUtil
// 6.7% = 10.2 x (46/73): pure stall. Direct-from-global MFMA operands need
// >=1 iteration of prefetch distance; global_load_lds staging provides the
// async window for free. Do not retry A-direct without a pipelined prefetch.
template <bool OUT_BF16, bool A_F32>
__global__ __launch_bounds__(256) void gemm_bt_kernel(
    const void* __restrict__ A, const u16* __restrict__ B,
    const float* __restrict__ bias, void* __restrict__ C,
    int M, int N, int K) {
  __shared__ u16 sA[128 * 32];
  __shared__ u16 sB[128 * 32];
  const int tid = threadIdx.x;
  const int m0 = blockIdx.x * 128;
  const int n0 = blockIdx.y * 128;
  const int w = tid >> 6;
  const int lane = tid & 63;
  const int wr = (w >> 1) * 64;
  const int wc = (w & 1) * 64;
  const int lm = lane & 15;
  const int lk = (lane >> 4) * 8;

  f32x4 acc[4][4] = {};

  const int srow = tid >> 2;
  const int ssub = (tid & 3) * 8;
  const u16* Ag = (const u16*)A + (size_t)(m0 + srow) * K + ssub;
  const float* Agf = (const float*)A + (size_t)(m0 + srow) * K + ssub;
  const u16* Bg = B + (size_t)(n0 + srow) * K + ssub;
  const size_t rstep = (size_t)64 * K;

  for (int k0 = 0; k0 < K; k0 += 32) {
    f32x4 a00, a01, a10, a11;
    if constexpr (A_F32) {
      // global f32 loads issued before the barrier: overlap prev step's MFMAs
      a00 = *(const f32x4*)(Agf + k0);
      a01 = *(const f32x4*)(Agf + k0 + 4);
      a10 = *(const f32x4*)(Agf + rstep + k0);
      a11 = *(const f32x4*)(Agf + rstep + k0 + 4);
    }
    __syncthreads();
    if constexpr (A_F32) {
      u32x4 w0, w1;
      w0[0] = cvtpk(a00[0], a00[1]); w0[1] = cvtpk(a00[2], a00[3]);
      w0[2] = cvtpk(a01[0], a01[1]); w0[3] = cvtpk(a01[2], a01[3]);
      w1[0] = cvtpk(a10[0], a10[1]); w1[1] = cvtpk(a10[2], a10[3]);
      w1[2] = cvtpk(a11[0], a11[1]); w1[3] = cvtpk(a11[2], a11[3]);
      *(u32x4*)&sA[tid * 8] = w0;
      *(u32x4*)&sA[2048 + tid * 8] = w1;
    } else {
      lds_async16(Ag + k0, &sA[tid * 8]);
      lds_async16(Ag + rstep + k0, &sA[2048 + tid * 8]);
    }
    lds_async16(Bg + k0, &sB[tid * 8]);
    lds_async16(Bg + rstep + k0, &sB[2048 + tid * 8]);
    __syncthreads();
    bf16x8 af[4], bfr[4];
#pragma unroll
    for (int i = 0; i < 4; ++i)
      af[i] = *(const bf16x8*)&sA[(wr + i * 16 + lm) * 32 + lk];
#pragma unroll
    for (int j = 0; j < 4; ++j)
      bfr[j] = *(const bf16x8*)&sB[(wc + j * 16 + lm) * 32 + lk];
#pragma unroll
    for (int i = 0; i < 4; ++i)
#pragma unroll
      for (int j = 0; j < 4; ++j)
        acc[i][j] = __builtin_amdgcn_mfma_f32_16x16x32_bf16(af[i], bfr[j], acc[i][j], 0, 0, 0);
  }

  const int r0 = (lane >> 4) * 4;
#pragma unroll
  for (int j = 0; j < 4; ++j) {
    const int n = n0 + wc + j * 16 + lm;
    const float bv = bias[n];
#pragma unroll
    for (int i = 0; i < 4; ++i) {
#pragma unroll
      for (int r = 0; r < 4; ++r) {
        const int m = m0 + wr + i * 16 + r0 + r;
        float v = acc[i][j][r] + bv;
        if (OUT_BF16)
          ((u16*)C)[(size_t)m * N + n] = f2bf(v);
        else
          ((float*)C)[(size_t)m * N + n] = v;
      }
    }
  }
}

// ---------------- fused per-(block,head) attention ----------------
// ROUND-2 EXACT SOURCE (proven 44.5-44.9us, VGPR 64). Do not "improve"
// without a within-session A/B.
// LEDGER (measured):
//  r2 44.9us: sVt col XOR-swizzle; cvt_pk packing; denominator via
//    mfma(P, ones); 1-deep K prefetch; setprio; single sP + WAR fence.
//  r3 48.0us REGRESSED: sP hf-dbuf + V-reg-prefetch -> VGPR 68 crossed the
//    64-VGPR allocation cliff (8->7 waves/SIMD), occ 31->24%.
//  r4 48.0us: sP-XOR changed conflict count by exactly 0 -> conflicts are
//    NOT sP; V-prefetch's +4 VGPR was the whole r3 regression.
//    LESSON: stay at VGPR <= 64.
//  r5 FAILED (absmax 0.19): K-row re-tiling to keep PV A-fragment in regs.
//    OPEN MYSTERY — do not retry without disasm evidence.
// launch_bounds(256,2): (256,4) spilled catastrophically. `#pragma unroll 1`
// on the ch loop is load-bearing: full unroll hoists all kf loads and spills.
// The asm memory fence pins the P-tile read -> overwrite (WAR) order.
__global__ __launch_bounds__(256, 2) void attn_kernel(const u16* __restrict__ qkv,
                                                      u16* __restrict__ o_ws) {
  __shared__ u16 sVt[32 * 264];   // V transposed, stride 264 u16, cols XOR-swizzled
  __shared__ u16 sP[4 * 32 * 40]; // per-wave P half-tile: 32 rows x 40 u16

  const int bid = blockIdx.x;
  const int n = bid >> 3;
  const int h = bid & 7;
  const int rowbase = (n >> 5) * 4224 + (n & 31) * 128;
  const int tid = threadIdx.x;
  const int w = tid >> 6;
  const int lane = tid & 63;
  const int lm = lane & 15;
  const int lg = lane >> 4;

  // stage V transposed for this head: V[j][d] -> sVt[d*264 + (j ^ ((d>>3)<<4))]
#pragma unroll
  for (int it = 0; it < 4; ++it) {
    int c = it * 256 + tid;
    int row = c >> 2;
    int sub = (c & 3) * 8;
    int rsw = row ^ ((sub >> 3) << 4);   // swizzled column; (d>>3) is sub>>3 for all 8 d
    const u16* gv = qkv + (size_t)(rowbase + row) * 768 + 512 + h * 32 + sub;
    u32x4 vv = *(const u32x4*)gv;
#pragma unroll
    for (int q = 0; q < 4; ++q) {
      sVt[(sub + 2 * q) * 264 + rsw] = (u16)(vv[q] & 0xFFFFu);
      sVt[(sub + 2 * q + 1) * 264 + rsw] = (u16)(vv[q] >> 16);
    }
  }

  // Q fragments straight from global (wave-private rows; 16 rows x 64B contiguous)
  bf16x8 qf[4];
#pragma unroll
  for (int rt = 0; rt < 4; ++rt) {
    int row = rowbase + w * 64 + rt * 16 + lm;
    qf[rt] = *(const bf16x8*)(qkv + (size_t)row * 768 + h * 32 + lg * 8);
  }

  const u16* kbase = qkv + (size_t)(rowbase + lm) * 768 + 256 + h * 32 + lg * 8;

  // prime K prefetch for ch=0 (overlaps the staging barrier)
  bf16x8 kfc[2];
#pragma unroll
  for (int ct = 0; ct < 2; ++ct)
    kfc[ct] = *(const bf16x8*)(kbase + (size_t)(ct * 16) * 768);

  __syncthreads();

  f32x4 oacc[4][2] = {};
  f32x4 lacc[4] = {};   // softmax denominators via mfma(P, ones)
  u16* myP = sP + w * (32 * 40);
  const float C1 = 0.25500035370494726f; // scale * log2(e)
  const float C2 = 1.4426950408889634f;  // log2(e)
  const int jq = lg * 4;
  const int D0w = w * 64;
  const bf16x8 onesb = {(short)0x3F80, (short)0x3F80, (short)0x3F80, (short)0x3F80,
                        (short)0x3F80, (short)0x3F80, (short)0x3F80, (short)0x3F80};

#pragma unroll 1
  for (int ch = 0; ch < 8; ++ch) {
    // prefetch next chunk's K fragments (clamped; last iter loads are dead)
    const int chn = (ch < 7) ? ch + 1 : 7;
    bf16x8 kfn[2], vf[2];
#pragma unroll
    for (int ct = 0; ct < 2; ++ct)
      kfn[ct] = *(const bf16x8*)(kbase + (size_t)(chn * 32 + ct * 16) * 768);
#pragma unroll
    for (int ctd = 0; ctd < 2; ++ctd) {
      int d = ctd * 16 + lm;
      vf[ctd] = *(const bf16x8*)&sVt[d * 264 + ((ch * 32 + lg * 8) ^ ((d >> 3) << 4))];
    }

#pragma unroll
    for (int hf = 0; hf < 2; ++hf) {
#pragma unroll
      for (int ct = 0; ct < 2; ++ct) {
#pragma unroll
        for (int rl = 0; rl < 2; ++rl) {
          const int rt = hf * 2 + rl;
          f32x4 s = __builtin_amdgcn_mfma_f32_16x16x32_bf16(kfc[ct], qf[rt], f32x4{0.f, 0.f, 0.f, 0.f}, 0, 0, 0);
          const int D0 = D0w + rt * 16 - (ch * 32 + ct * 16); // wave-uniform
          float p0, p1, p2, p3;
          if (D0 >= 16 && D0 <= 112) {        // fully in-band: +1 bias
            p0 = fexp2(__builtin_fmaf(s[0], C1, C2));
            p1 = fexp2(__builtin_fmaf(s[1], C1, C2));
            p2 = fexp2(__builtin_fmaf(s[2], C1, C2));
            p3 = fexp2(__builtin_fmaf(s[3], C1, C2));
          } else if (D0 == 0) {               // diagonal: in-band iff lm >= jq+r
            p0 = fexp2(__builtin_fmaf(s[0], C1, (lm >= jq + 0) ? C2 : 0.0f));
            p1 = fexp2(__builtin_fmaf(s[1], C1, (lm >= jq + 1) ? C2 : 0.0f));
            p2 = fexp2(__builtin_fmaf(s[2], C1, (lm >= jq + 2) ? C2 : 0.0f));
            p3 = fexp2(__builtin_fmaf(s[3], C1, (lm >= jq + 3) ? C2 : 0.0f));
          } else if (D0 == 128) {             // far edge: in-band iff lm < jq+r
            p0 = fexp2(__builtin_fmaf(s[0], C1, (lm < jq + 0) ? C2 : 0.0f));
            p1 = fexp2(__builtin_fmaf(s[1], C1, (lm < jq + 1) ? C2 : 0.0f));
            p2 = fexp2(__builtin_fmaf(s[2], C1, (lm < jq + 2) ? C2 : 0.0f));
            p3 = fexp2(__builtin_fmaf(s[3], C1, (lm < jq + 3) ? C2 : 0.0f));
          } else {                            // fully out of band: no bias
            p0 = fexp2(s[0] * C1);
            p1 = fexp2(s[1] * C1);
            p2 = fexp2(s[2] * C1);
            p3 = fexp2(s[3] * C1);
          }
          u32 a0, a1;
          asm("v_cvt_pk_bf16_f32 %0, %1, %2" : "=v"(a0) : "v"(p0), "v"(p1));
          asm("v_cvt_pk_bf16_f32 %0, %1, %2" : "=v"(a1) : "v"(p2), "v"(p3));
          u32x2 pk;
          pk[0] = a0;
          pk[1] = a1;
          *(u32x2*)&myP[(rl * 16 + lm) * 40 + ct * 16 + jq] = pk;
        }
      }
      // O(half) += P(half) * Vc ; lsum(half) += P(half) . 1  (wave-private P)
      bf16x8 pf[2];
#pragma unroll
      for (int rl = 0; rl < 2; ++rl)
        pf[rl] = *(const bf16x8*)&myP[(rl * 16 + lm) * 40 + lg * 8];
      // pin WAR order: these reads must precede the next half's overwrites
      __asm__ __volatile__("" ::: "memory");
      __builtin_amdgcn_s_setprio(1);
#pragma unroll
      for (int rl = 0; rl < 2; ++rl) {
        lacc[hf * 2 + rl] =
            __builtin_amdgcn_mfma_f32_16x16x32_bf16(pf[rl], onesb, lacc[hf * 2 + rl], 0, 0, 0);
#pragma unroll
        for (int ctd = 0; ctd < 2; ++ctd)
          oacc[hf * 2 + rl][ctd] =
              __builtin_amdgcn_mfma_f32_16x16x32_bf16(pf[rl], vf[ctd], oacc[hf * 2 + rl][ctd], 0, 0, 0);
      }
      __builtin_amdgcn_s_setprio(0);
    }
    kfc[0] = kfn[0];
    kfc[1] = kfn[1];
  }

  // normalize + store; lacc[rt][r] holds the full denominator for row
  // i = rt*16 + lg*4 + r (C/D layout row = lg*4+r), exactly the epilogue row.
#pragma unroll
  for (int rt = 0; rt < 4; ++rt) {
#pragma unroll
    for (int r = 0; r < 4; ++r) {
      float inv = 1.0f / lacc[rt][r];
      int i_g = w * 64 + rt * 16 + jq + r;
#pragma unroll
      for (int ctd = 0; ctd < 2; ++ctd) {
        float v = oacc[rt][ctd][r] * inv;
        u32 u = __builtin_bit_cast(u32, v) + 0x8000u;
        o_ws[((size_t)(n * 256 + i_g)) * 256 + h * 32 + ctd * 16 + lm] = (u16)(u >> 16);
      }
    }
  }
}

// ---------------- overlap-add combine: oc[t] = sum(covering o_ws)/cnt ----------------
__global__ void combine_kernel(const u16* __restrict__ o_ws, u16* __restrict__ oc) {
  int gid = blockIdx.x * 256 + threadIdx.x;
  int m = gid >> 5;             // global row (bc*4224 + t)
  int f0 = (gid & 31) << 3;     // 8 features per thread
  int bc = m / 4224;
  int t = m - bc * 4224;
  int i0 = t >> 7;
  float a[8] = {0.f, 0.f, 0.f, 0.f, 0.f, 0.f, 0.f, 0.f};
  if (i0 <= 31) {
    const u16* p = o_ws + ((size_t)((bc * 32 + i0) * 256 + (t - (i0 << 7)))) * 256 + f0;
    u32x4 v = *(const u32x4*)p;
#pragma unroll
    for (int q = 0; q < 4; ++q) {
      a[2 * q] += bf2f((u16)(v[q] & 0xFFFFu));
      a[2 * q + 1] += bf2f((u16)(v[q] >> 16));
    }
  }
  if (i0 >= 1) {
    int i1 = i0 - 1;
    const u16* p = o_ws + ((size_t)((bc * 32 + i1) * 256 + (t - (i1 << 7)))) * 256 + f0;
    u32x4 v = *(const u32x4*)p;
#pragma unroll
    for (int q = 0; q < 4; ++q) {
      a[2 * q] += bf2f((u16)(v[q] & 0xFFFFu));
      a[2 * q + 1] += bf2f((u16)(v[q] >> 16));
    }
  }
  float sc = (i0 >= 1 && i0 <= 31) ? 0.5f : 1.0f;
  u32x2 o;
  o[0] = (u32)f2bf(a[0] * sc) | ((u32)f2bf(a[1] * sc) << 16);
  o[1] = (u32)f2bf(a[2] * sc) | ((u32)f2bf(a[3] * sc) << 16);
  u32x2 o2;
  o2[0] = (u32)f2bf(a[4] * sc) | ((u32)f2bf(a[5] * sc) << 16);
  o2[1] = (u32)f2bf(a[6] * sc) | ((u32)f2bf(a[7] * sc) << 16);
  u16* dst = oc + (size_t)m * 256 + f0;
  *(u32x2*)dst = o;
  *(u32x2*)(dst + 4) = o2;
}

extern "C" void kernel_launch(void* const* d_in, const int* in_sizes, int n_in,
                              void* d_out, int out_size, void* d_ws, size_t ws_size,
                              hipStream_t stream) {
  const float* x = (const float*)d_in[0];
  const float* w_in = (const float*)d_in[1];
  const float* b_in = (const float*)d_in[2];
  const float* w_out = (const float*)d_in[3];
  const float* b_out = (const float*)d_in[4];
  float* y = (float*)d_out;
  char* ws = (char*)d_ws;

  // workspace layout (bytes)
  u16* qkv = (u16*)(ws);                   // 33792*768*2   = 51,904,512
  u16* xbf = (u16*)(ws + 51904512);        // 33792*256*2   = 17,301,504 (oc only)
  u16* ows = (u16*)(ws + 69206016);        // 256*256*256*2 = 33,554,432
  u16* winb = (u16*)(ws + 102760448);      // 768*256*2     = 393,216
  u16* woutb = (u16*)(ws + 103153664);     // 256*256*2     = 131,072  (end 103,284,736)

  cvt2_kernel<<<256, 256, 0, stream>>>(w_in, w_out, winb, woutb, 49152, 16384);

  // qkv = x @ w_in^T + b_in — A read directly from f32 x, converted in staging
  // (RNE cvt_pk == f2bf, so qkv is bitwise identical to the old cvt+gemm path)
  gemm_bt_kernel<true, true><<<dim3(264, 6), 256, 0, stream>>>(x, winb, b_in, qkv, 33792, 768, 256);

  // per-(block, head) attention
  attn_kernel<<<2048, 256, 0, stream>>>(qkv, ows);

  // overlap-add + count division (commutes with the linear w_out projection)
  combine_kernel<<<4224, 256, 0, stream>>>(ows, xbf);

  // y = oc @ w_out^T + b_out
  gemm_bt_kernel<false, false><<<dim3(264, 2), 256, 0, stream>>>(xbf, woutb, b_out, y, 33792, 256, 256);
}

// Round 11
// 174.991 us; speedup vs baseline: 1.1897x; 1.0308x over previous
//
#include <hip/hip_runtime.h>

typedef unsigned short u16;
typedef unsigned int u32;
typedef __attribute__((ext_vector_type(8))) short bf16x8;
typedef __attribute__((ext_vector_type(4))) float f32x4;
typedef __attribute__((ext_vector_type(4))) u32 u32x4;
typedef __attribute__((ext_vector_type(2))) u32 u32x2;

__device__ __forceinline__ u16 f2bf(float f) {
  u32 u = __builtin_bit_cast(u32, f);
  return (u16)((u + 0x7FFFu + ((u >> 16) & 1u)) >> 16);
}
__device__ __forceinline__ float bf2f(u16 b) {
  return __builtin_bit_cast(float, (u32)b << 16);
}

// v_cvt_pk_bf16_f32 = RNE, bitwise-identical to f2bf for finite inputs
// (proven: r6 fused gemm1 kept absmax exactly 0.001953125).
__device__ __forceinline__ u32 cvtpk(float lo, float hi) {
  u32 r;
  asm("v_cvt_pk_bf16_f32 %0, %1, %2" : "=v"(r) : "v"(lo), "v"(hi));
  return r;
}

__device__ __forceinline__ float fexp2(float x) {
#if __has_builtin(__builtin_amdgcn_exp2f)
  return __builtin_amdgcn_exp2f(x);
#else
  return __expf(x * 0.6931471805599453f);
#endif
}

__device__ __forceinline__ void lds_async16(const void* g, void* l) {
  auto gp = reinterpret_cast<const __attribute__((address_space(1))) u32*>(
      reinterpret_cast<uintptr_t>(g));
  auto lp = reinterpret_cast<__attribute__((address_space(3))) u32*>(
      reinterpret_cast<uintptr_t>(l));
  __builtin_amdgcn_global_load_lds(gp, lp, 16, 0, 0);
}

// two small weight converts in one launch
__global__ void cvt2_kernel(const float* __restrict__ a, const float* __restrict__ b,
                            u16* __restrict__ oa, u16* __restrict__ ob, int na4, int nb4) {
  int i = blockIdx.x * 256 + threadIdx.x;
  const float* src;
  u16* dst;
  int idx;
  if (i < na4) {
    src = a; dst = oa; idx = i;
  } else {
    idx = i - na4;
    if (idx >= nb4) return;
    src = b; dst = ob;
  }
  f32x4 v = *(const f32x4*)(src + (size_t)idx * 4);
  u32x2 o;
  o[0] = (u32)f2bf(v[0]) | ((u32)f2bf(v[1]) << 16);
  o[1] = (u32)f2bf(v[2]) | ((u32)f2bf(v[3]) << 16);
  *(u32x2*)(dst + (size_t)idx * 4) = o;
}

// ---------------- GEMM: C[m][n] = sum_k A[m][k]*B[n][k] + bias[n] ----------------
// EXACT r6 version (proven passing, total 179.6us). gemm1 uses A_F32=true:
// A staged from f32 global via reg-load (issued BEFORE the WAR barrier, so
// HBM latency overlaps the previous k-step's MFMAs) + cvtpk + ds_write.
// Operand swap mfma(bfr, af) produced absmax 1.01 — reverted permanently.
// Do NOT swap the mfma operand order here.
// LEDGER r9 (measured, FAILED): A-fragments DIRECT from global f32 per
// k-step (no LDS, sB dbuf, 1 barrier) = 73.2us vs 46 — MfmaUtil 6.7%: pure
// stall. Direct-from-global MFMA operands need >=1 iteration of prefetch
// distance; global_load_lds / reg-load-before-barrier provides the window.
template <bool OUT_BF16, bool A_F32>
__global__ __launch_bounds__(256) void gemm_bt_kernel(
    const void* __restrict__ A, const u16* __restrict__ B,
    const float* __restrict__ bias, void* __restrict__ C,
    int M, int N, int K) {
  __shared__ u16 sA[128 * 32];
  __shared__ u16 sB[128 * 32];
  const int tid = threadIdx.x;
  const int m0 = blockIdx.x * 128;
  const int n0 = blockIdx.y * 128;
  const int w = tid >> 6;
  const int lane = tid & 63;
  const int wr = (w >> 1) * 64;
  const int wc = (w & 1) * 64;
  const int lm = lane & 15;
  const int lk = (lane >> 4) * 8;

  f32x4 acc[4][4] = {};

  const int srow = tid >> 2;
  const int ssub = (tid & 3) * 8;
  const u16* Ag = (const u16*)A + (size_t)(m0 + srow) * K + ssub;
  const float* Agf = (const float*)A + (size_t)(m0 + srow) * K + ssub;
  const u16* Bg = B + (size_t)(n0 + srow) * K + ssub;
  const size_t rstep = (size_t)64 * K;

  for (int k0 = 0; k0 < K; k0 += 32) {
    f32x4 a00, a01, a10, a11;
    if constexpr (A_F32) {
      // global f32 loads issued before the barrier: overlap prev step's MFMAs
      a00 = *(const f32x4*)(Agf + k0);
      a01 = *(const f32x4*)(Agf + k0 + 4);
      a10 = *(const f32x4*)(Agf + rstep + k0);
      a11 = *(const f32x4*)(Agf + rstep + k0 + 4);
    }
    __syncthreads();
    if constexpr (A_F32) {
      u32x4 w0, w1;
      w0[0] = cvtpk(a00[0], a00[1]); w0[1] = cvtpk(a00[2], a00[3]);
      w0[2] = cvtpk(a01[0], a01[1]); w0[3] = cvtpk(a01[2], a01[3]);
      w1[0] = cvtpk(a10[0], a10[1]); w1[1] = cvtpk(a10[2], a10[3]);
      w1[2] = cvtpk(a11[0], a11[1]); w1[3] = cvtpk(a11[2], a11[3]);
      *(u32x4*)&sA[tid * 8] = w0;
      *(u32x4*)&sA[2048 + tid * 8] = w1;
    } else {
      lds_async16(Ag + k0, &sA[tid * 8]);
      lds_async16(Ag + rstep + k0, &sA[2048 + tid * 8]);
    }
    lds_async16(Bg + k0, &sB[tid * 8]);
    lds_async16(Bg + rstep + k0, &sB[2048 + tid * 8]);
    __syncthreads();
    bf16x8 af[4], bfr[4];
#pragma unroll
    for (int i = 0; i < 4; ++i)
      af[i] = *(const bf16x8*)&sA[(wr + i * 16 + lm) * 32 + lk];
#pragma unroll
    for (int j = 0; j < 4; ++j)
      bfr[j] = *(const bf16x8*)&sB[(wc + j * 16 + lm) * 32 + lk];
#pragma unroll
    for (int i = 0; i < 4; ++i)
#pragma unroll
      for (int j = 0; j < 4; ++j)
        acc[i][j] = __builtin_amdgcn_mfma_f32_16x16x32_bf16(af[i], bfr[j], acc[i][j], 0, 0, 0);
  }

  const int r0 = (lane >> 4) * 4;
#pragma unroll
  for (int j = 0; j < 4; ++j) {
    const int n = n0 + wc + j * 16 + lm;
    const float bv = bias[n];
#pragma unroll
    for (int i = 0; i < 4; ++i) {
#pragma unroll
      for (int r = 0; r < 4; ++r) {
        const int m = m0 + wr + i * 16 + r0 + r;
        float v = acc[i][j][r] + bv;
        if (OUT_BF16)
          ((u16*)C)[(size_t)m * N + n] = f2bf(v);
        else
          ((float*)C)[(size_t)m * N + n] = v;
      }
    }
  }
}

// ---------------- GEMM2 fused with overlap-add combine ----------------
// y[m] = (sum of covering ows rows / cnt) @ w_out^T + b_out, computed WITHOUT
// materializing oc. Round-11 observation: gemm2's 128-row blocks align with
// the overlap structure — for block x: bc = x/33, i0 = x%33 is BLOCK-UNIFORM
// (4224 = 33*128), and the two covering ows slabs are contiguous 128-row
// ranges:
//   src0 = ows[(bc*32 + i0)*256 + rib]        (exists iff i0 <= 31)
//   src1 = ows[(bc*32 + i0-1)*256 + 128 + rib] (exists iff i0 >= 1)
//   oc[m] = f2bf((src0 + src1) * sc), sc = both ? 0.5 : 1.0
// Numerics: sc=0.5 is a power of two -> commutes exactly with bf16 rounding
// and with the (linear) MFMA, so it moves to the epilogue fmaf(sc, acc, bv);
// bf16(sum)*0.5 == bf16(0.5*sum) bitwise (normal range). Single-source
// blocks stage the raw bf16 (f2bf(bf2f(v)) == v). Result is bitwise
// identical to the combine_kernel + gemm path. Deletes one full HBM pass
// (oc write+read = 34.6MB) and a launch.
// A-loads issued BEFORE the WAR barrier (r6-proven pattern; r9's stall trap
// needs >=1 iter prefetch distance, which the pre-barrier issue provides).
// mfma operand order / fragments / epilogue layout verbatim from the proven
// kernel. Revert criterion: absmax change or total >= 180us.
__global__ __launch_bounds__(256) void gemm2_fused_kernel(
    const u16* __restrict__ ows, const u16* __restrict__ B,
    const float* __restrict__ bias, float* __restrict__ C,
    int M, int N, int K) {
  __shared__ u16 sA[128 * 32];
  __shared__ u16 sB[128 * 32];
  const int tid = threadIdx.x;
  const int x = blockIdx.x;
  const int m0 = x * 128;
  const int n0 = blockIdx.y * 128;
  const int bc = x / 33;
  const int ib = x - bc * 33;          // = i0, block-uniform
  const bool has0 = (ib <= 31);
  const bool has1 = (ib >= 1);
  const float sc = (has0 && has1) ? 0.5f : 1.0f;
  const int w = tid >> 6;
  const int lane = tid & 63;
  const int wr = (w >> 1) * 64;
  const int wc = (w & 1) * 64;
  const int lm = lane & 15;
  const int lk = (lane >> 4) * 8;

  f32x4 acc[4][4] = {};

  const int srow = tid >> 2;
  const int ssub = (tid & 3) * 8;
  const u16* A0 = ows + ((size_t)((bc * 32 + ib) * 256 + srow)) * 256 + ssub;
  const u16* A1 = ows + ((size_t)((bc * 32 + ib - 1) * 256 + 128 + srow)) * 256 + ssub;
  const size_t arstep = (size_t)64 * 256;
  const u16* Bg = B + (size_t)(n0 + srow) * K + ssub;
  const size_t rstep = (size_t)64 * K;

  for (int k0 = 0; k0 < K; k0 += 32) {
    u32x4 a00{}, a01{}, a10{}, a11{};
    // global loads issued before the barrier: overlap prev step's MFMAs
    if (has0) {
      a00 = *(const u32x4*)(A0 + k0);
      a01 = *(const u32x4*)(A0 + arstep + k0);
    }
    if (has1) {
      a10 = *(const u32x4*)(A1 + k0);
      a11 = *(const u32x4*)(A1 + arstep + k0);
    }
    __syncthreads();
    if (has0 && has1) {
      u32x4 w0, w1;
#pragma unroll
      for (int q = 0; q < 4; ++q) {
        float e0 = __builtin_bit_cast(float, a00[q] << 16) +
                   __builtin_bit_cast(float, a10[q] << 16);
        float o0 = __builtin_bit_cast(float, a00[q] & 0xFFFF0000u) +
                   __builtin_bit_cast(float, a10[q] & 0xFFFF0000u);
        w0[q] = cvtpk(e0, o0);
        float e1 = __builtin_bit_cast(float, a01[q] << 16) +
                   __builtin_bit_cast(float, a11[q] << 16);
        float o1 = __builtin_bit_cast(float, a01[q] & 0xFFFF0000u) +
                   __builtin_bit_cast(float, a11[q] & 0xFFFF0000u);
        w1[q] = cvtpk(e1, o1);
      }
      *(u32x4*)&sA[tid * 8] = w0;
      *(u32x4*)&sA[2048 + tid * 8] = w1;
    } else if (has0) {
      *(u32x4*)&sA[tid * 8] = a00;
      *(u32x4*)&sA[2048 + tid * 8] = a01;
    } else {
      *(u32x4*)&sA[tid * 8] = a10;
      *(u32x4*)&sA[2048 + tid * 8] = a11;
    }
    lds_async16(Bg + k0, &sB[tid * 8]);
    lds_async16(Bg + rstep + k0, &sB[2048 + tid * 8]);
    __syncthreads();
    bf16x8 af[4], bfr[4];
#pragma unroll
    for (int i = 0; i < 4; ++i)
      af[i] = *(const bf16x8*)&sA[(wr + i * 16 + lm) * 32 + lk];
#pragma unroll
    for (int j = 0; j < 4; ++j)
      bfr[j] = *(const bf16x8*)&sB[(wc + j * 16 + lm) * 32 + lk];
#pragma unroll
    for (int i = 0; i < 4; ++i)
#pragma unroll
      for (int j = 0; j < 4; ++j)
        acc[i][j] = __builtin_amdgcn_mfma_f32_16x16x32_bf16(af[i], bfr[j], acc[i][j], 0, 0, 0);
  }

  const int r0 = (lane >> 4) * 4;
#pragma unroll
  for (int j = 0; j < 4; ++j) {
    const int n = n0 + wc + j * 16 + lm;
    const float bv = bias[n];
#pragma unroll
    for (int i = 0; i < 4; ++i) {
#pragma unroll
      for (int r = 0; r < 4; ++r) {
        const int m = m0 + wr + i * 16 + r0 + r;
        C[(size_t)m * N + n] = __builtin_fmaf(sc, acc[i][j][r], bv);
      }
    }
  }
}

// ---------------- fused per-(block,head) attention ----------------
// ROUND-2 EXACT SOURCE (proven 44.3-44.9us, VGPR 64). Do not "improve"
// without a within-session A/B.
// LEDGER (measured):
//  r2 44.9us: sVt col XOR-swizzle; cvt_pk packing; denominator via
//    mfma(P, ones); 1-deep K prefetch; setprio; single sP + WAR fence.
//  r3 48.0us REGRESSED: sP hf-dbuf + V-reg-prefetch -> VGPR 68 crossed the
//    64-VGPR allocation cliff (8->7 waves/SIMD), occ 31->24%.
//  r4 48.0us: sP-XOR changed conflict count by exactly 0 -> conflicts are
//    NOT sP; V-prefetch's +4 VGPR was the whole r3 regression.
//    LESSON: stay at VGPR <= 64.
//  r5 FAILED (absmax 0.19): K-row re-tiling to keep PV A-fragment in regs.
//    OPEN MYSTERY — do not retry without disasm evidence.
// launch_bounds(256,2): (256,4) spilled catastrophically. `#pragma unroll 1`
// on the ch loop is load-bearing: full unroll hoists all kf loads and spills.
// The asm memory fence pins the P-tile read -> overwrite (WAR) order.
__global__ __launch_bounds__(256, 2) void attn_kernel(const u16* __restrict__ qkv,
                                                      u16* __restrict__ o_ws) {
  __shared__ u16 sVt[32 * 264];   // V transposed, stride 264 u16, cols XOR-swizzled
  __shared__ u16 sP[4 * 32 * 40]; // per-wave P half-tile: 32 rows x 40 u16

  const int bid = blockIdx.x;
  const int n = bid >> 3;
  const int h = bid & 7;
  const int rowbase = (n >> 5) * 4224 + (n & 31) * 128;
  const int tid = threadIdx.x;
  const int w = tid >> 6;
  const int lane = tid & 63;
  const int lm = lane & 15;
  const int lg = lane >> 4;

  // stage V transposed for this head: V[j][d] -> sVt[d*264 + (j ^ ((d>>3)<<4))]
#pragma unroll
  for (int it = 0; it < 4; ++it) {
    int c = it * 256 + tid;
    int row = c >> 2;
    int sub = (c & 3) * 8;
    int rsw = row ^ ((sub >> 3) << 4);   // swizzled column; (d>>3) is sub>>3 for all 8 d
    const u16* gv = qkv + (size_t)(rowbase + row) * 768 + 512 + h * 32 + sub;
    u32x4 vv = *(const u32x4*)gv;
#pragma unroll
    for (int q = 0; q < 4; ++q) {
      sVt[(sub + 2 * q) * 264 + rsw] = (u16)(vv[q] & 0xFFFFu);
      sVt[(sub + 2 * q + 1) * 264 + rsw] = (u16)(vv[q] >> 16);
    }
  }

  // Q fragments straight from global (wave-private rows; 16 rows x 64B contiguous)
  bf16x8 qf[4];
#pragma unroll
  for (int rt = 0; rt < 4; ++rt) {
    int row = rowbase + w * 64 + rt * 16 + lm;
    qf[rt] = *(const bf16x8*)(qkv + (size_t)row * 768 + h * 32 + lg * 8);
  }

  const u16* kbase = qkv + (size_t)(rowbase + lm) * 768 + 256 + h * 32 + lg * 8;

  // prime K prefetch for ch=0 (overlaps the staging barrier)
  bf16x8 kfc[2];
#pragma unroll
  for (int ct = 0; ct < 2; ++ct)
    kfc[ct] = *(const bf16x8*)(kbase + (size_t)(ct * 16) * 768);

  __syncthreads();

  f32x4 oacc[4][2] = {};
  f32x4 lacc[4] = {};   // softmax denominators via mfma(P, ones)
  u16* myP = sP + w * (32 * 40);
  const float C1 = 0.25500035370494726f; // scale * log2(e)
  const float C2 = 1.4426950408889634f;  // log2(e)
  const int jq = lg * 4;
  const int D0w = w * 64;
  const bf16x8 onesb = {(short)0x3F80, (short)0x3F80, (short)0x3F80, (short)0x3F80,
                        (short)0x3F80, (short)0x3F80, (short)0x3F80, (short)0x3F80};

#pragma unroll 1
  for (int ch = 0; ch < 8; ++ch) {
    // prefetch next chunk's K fragments (clamped; last iter loads are dead)
    const int chn = (ch < 7) ? ch + 1 : 7;
    bf16x8 kfn[2], vf[2];
#pragma unroll
    for (int ct = 0; ct < 2; ++ct)
      kfn[ct] = *(const bf16x8*)(kbase + (size_t)(chn * 32 + ct * 16) * 768);
#pragma unroll
    for (int ctd = 0; ctd < 2; ++ctd) {
      int d = ctd * 16 + lm;
      vf[ctd] = *(const bf16x8*)&sVt[d * 264 + ((ch * 32 + lg * 8) ^ ((d >> 3) << 4))];
    }

#pragma unroll
    for (int hf = 0; hf < 2; ++hf) {
#pragma unroll
      for (int ct = 0; ct < 2; ++ct) {
#pragma unroll
        for (int rl = 0; rl < 2; ++rl) {
          const int rt = hf * 2 + rl;
          f32x4 s = __builtin_amdgcn_mfma_f32_16x16x32_bf16(kfc[ct], qf[rt], f32x4{0.f, 0.f, 0.f, 0.f}, 0, 0, 0);
          const int D0 = D0w + rt * 16 - (ch * 32 + ct * 16); // wave-uniform
          float p0, p1, p2, p3;
          if (D0 >= 16 && D0 <= 112) {        // fully in-band: +1 bias
            p0 = fexp2(__builtin_fmaf(s[0], C1, C2));
            p1 = fexp2(__builtin_fmaf(s[1], C1, C2));
            p2 = fexp2(__builtin_fmaf(s[2], C1, C2));
            p3 = fexp2(__builtin_fmaf(s[3], C1, C2));
          } else if (D0 == 0) {               // diagonal: in-band iff lm >= jq+r
            p0 = fexp2(__builtin_fmaf(s[0], C1, (lm >= jq + 0) ? C2 : 0.0f));
            p1 = fexp2(__builtin_fmaf(s[1], C1, (lm >= jq + 1) ? C2 : 0.0f));
            p2 = fexp2(__builtin_fmaf(s[2], C1, (lm >= jq + 2) ? C2 : 0.0f));
            p3 = fexp2(__builtin_fmaf(s[3], C1, (lm >= jq + 3) ? C2 : 0.0f));
          } else if (D0 == 128) {             // far edge: in-band iff lm < jq+r
            p0 = fexp2(__builtin_fmaf(s[0], C1, (lm < jq + 0) ? C2 : 0.0f));
            p1 = fexp2(__builtin_fmaf(s[1], C1, (lm < jq + 1) ? C2 : 0.0f));
            p2 = fexp2(__builtin_fmaf(s[2], C1, (lm < jq + 2) ? C2 : 0.0f));
            p3 = fexp2(__builtin_fmaf(s[3], C1, (lm < jq + 3) ? C2 : 0.0f));
          } else {                            // fully out of band: no bias
            p0 = fexp2(s[0] * C1);
            p1 = fexp2(s[1] * C1);
            p2 = fexp2(s[2] * C1);
            p3 = fexp2(s[3] * C1);
          }
          u32 a0, a1;
          asm("v_cvt_pk_bf16_f32 %0, %1, %2" : "=v"(a0) : "v"(p0), "v"(p1));
          asm("v_cvt_pk_bf16_f32 %0, %1, %2" : "=v"(a1) : "v"(p2), "v"(p3));
          u32x2 pk;
          pk[0] = a0;
          pk[1] = a1;
          *(u32x2*)&myP[(rl * 16 + lm) * 40 + ct * 16 + jq] = pk;
        }
      }
      // O(half) += P(half) * Vc ; lsum(half) += P(half) . 1  (wave-private P)
      bf16x8 pf[2];
#pragma unroll
      for (int rl = 0; rl < 2; ++rl)
        pf[rl] = *(const bf16x8*)&myP[(rl * 16 + lm) * 40 + lg * 8];
      // pin WAR order: these reads must precede the next half's overwrites
      __asm__ __volatile__("" ::: "memory");
      __builtin_amdgcn_s_setprio(1);
#pragma unroll
      for (int rl = 0; rl < 2; ++rl) {
        lacc[hf * 2 + rl] =
            __builtin_amdgcn_mfma_f32_16x16x32_bf16(pf[rl], onesb, lacc[hf * 2 + rl], 0, 0, 0);
#pragma unroll
        for (int ctd = 0; ctd < 2; ++ctd)
          oacc[hf * 2 + rl][ctd] =
              __builtin_amdgcn_mfma_f32_16x16x32_bf16(pf[rl], vf[ctd], oacc[hf * 2 + rl][ctd], 0, 0, 0);
      }
      __builtin_amdgcn_s_setprio(0);
    }
    kfc[0] = kfn[0];
    kfc[1] = kfn[1];
  }

  // normalize + store; lacc[rt][r] holds the full denominator for row
  // i = rt*16 + lg*4 + r (C/D layout row = lg*4+r), exactly the epilogue row.
#pragma unroll
  for (int rt = 0; rt < 4; ++rt) {
#pragma unroll
    for (int r = 0; r < 4; ++r) {
      float inv = 1.0f / lacc[rt][r];
      int i_g = w * 64 + rt * 16 + jq + r;
#pragma unroll
      for (int ctd = 0; ctd < 2; ++ctd) {
        float v = oacc[rt][ctd][r] * inv;
        u32 u = __builtin_bit_cast(u32, v) + 0x8000u;
        o_ws[((size_t)(n * 256 + i_g)) * 256 + h * 32 + ctd * 16 + lm] = (u16)(u >> 16);
      }
    }
  }
}

extern "C" void kernel_launch(void* const* d_in, const int* in_sizes, int n_in,
                              void* d_out, int out_size, void* d_ws, size_t ws_size,
                              hipStream_t stream) {
  const float* x = (const float*)d_in[0];
  const float* w_in = (const float*)d_in[1];
  const float* b_in = (const float*)d_in[2];
  const float* w_out = (const float*)d_in[3];
  const float* b_out = (const float*)d_in[4];
  float* y = (float*)d_out;
  char* ws = (char*)d_ws;

  // workspace layout (bytes)
  u16* qkv = (u16*)(ws);                   // 33792*768*2   = 51,904,512
  u16* ows = (u16*)(ws + 69206016);        // 256*256*256*2 = 33,554,432
  u16* winb = (u16*)(ws + 102760448);      // 768*256*2     = 393,216
  u16* woutb = (u16*)(ws + 103153664);     // 256*256*2     = 131,072  (end 103,284,736)

  cvt2_kernel<<<256, 256, 0, stream>>>(w_in, w_out, winb, woutb, 49152, 16384);

  // qkv = x @ w_in^T + b_in — A read directly from f32 x, converted in staging
  // (RNE cvt_pk == f2bf, so qkv is bitwise identical to the old cvt+gemm path)
  gemm_bt_kernel<true, true><<<dim3(264, 6), 256, 0, stream>>>(x, winb, b_in, qkv, 33792, 768, 256);

  // per-(block, head) attention
  attn_kernel<<<2048, 256, 0, stream>>>(qkv, ows);

  // y = combine(ows) @ w_out^T + b_out — overlap-add fused into A-staging
  gemm2_fused_kernel<<<dim3(264, 2), 256, 0, stream>>>(ows, woutb, b_out, y, 33792, 256, 256);
}

// Round 12
// 168.859 us; speedup vs baseline: 1.2329x; 1.0363x over previous
//
#include <hip/hip_runtime.h>

typedef unsigned short u16;
typedef unsigned int u32;
typedef __attribute__((ext_vector_type(8))) short bf16x8;
typedef __attribute__((ext_vector_type(4))) float f32x4;
typedef __attribute__((ext_vector_type(4))) u32 u32x4;
typedef __attribute__((ext_vector_type(2))) u32 u32x2;

__device__ __forceinline__ u16 f2bf(float f) {
  u32 u = __builtin_bit_cast(u32, f);
  return (u16)((u + 0x7FFFu + ((u >> 16) & 1u)) >> 16);
}
__device__ __forceinline__ float bf2f(u16 b) {
  return __builtin_bit_cast(float, (u32)b << 16);
}

// v_cvt_pk_bf16_f32 = RNE, bitwise-identical to f2bf for finite inputs
// (proven: r6 fused gemm1 kept absmax exactly 0.001953125).
__device__ __forceinline__ u32 cvtpk(float lo, float hi) {
  u32 r;
  asm("v_cvt_pk_bf16_f32 %0, %1, %2" : "=v"(r) : "v"(lo), "v"(hi));
  return r;
}

__device__ __forceinline__ float fexp2(float x) {
#if __has_builtin(__builtin_amdgcn_exp2f)
  return __builtin_amdgcn_exp2f(x);
#else
  return __expf(x * 0.6931471805599453f);
#endif
}

__device__ __forceinline__ void lds_async16(const void* g, void* l) {
  auto gp = reinterpret_cast<const __attribute__((address_space(1))) u32*>(
      reinterpret_cast<uintptr_t>(g));
  auto lp = reinterpret_cast<__attribute__((address_space(3))) u32*>(
      reinterpret_cast<uintptr_t>(l));
  __builtin_amdgcn_global_load_lds(gp, lp, 16, 0, 0);
}

// two small weight converts in one launch
__global__ void cvt2_kernel(const float* __restrict__ a, const float* __restrict__ b,
                            u16* __restrict__ oa, u16* __restrict__ ob, int na4, int nb4) {
  int i = blockIdx.x * 256 + threadIdx.x;
  const float* src;
  u16* dst;
  int idx;
  if (i < na4) {
    src = a; dst = oa; idx = i;
  } else {
    idx = i - na4;
    if (idx >= nb4) return;
    src = b; dst = ob;
  }
  f32x4 v = *(const f32x4*)(src + (size_t)idx * 4);
  u32x2 o;
  o[0] = (u32)f2bf(v[0]) | ((u32)f2bf(v[1]) << 16);
  o[1] = (u32)f2bf(v[2]) | ((u32)f2bf(v[3]) << 16);
  *(u32x2*)(dst + (size_t)idx * 4) = o;
}

// ---------------- GEMM1 pipelined: qkv = x @ w_in^T + b_in, bf16 out --------
// Round-12 restructure of the latency-bound gemm1 (46.3us, MfmaUtil 10.4%):
// the r6 2-barrier structure exposed two un-overlapped waits per k-step —
// barrier1 waits the A f32 loads (issued one barrier earlier), barrier2
// drains the B global_load_lds issued immediately before it. Fix per r9's
// lesson (prefetch DISTANCE, not LDS removal): double-buffer sA+sB (32KB),
// ONE barrier per k-step. Iteration t:
//   barrier (drains stage of buf[cur] from iter t-1; WAR: buf[nxt] reads done)
//   issue A(t+1) f32 reg-loads  [AFTER the barrier so its vmcnt(0) drain
//                                doesn't serialize them]
//   ds_read af/bfr from buf[cur]; 16 MFMA   <- A/B(t+1) latency hides here
//   cvt A(t+1) + ds_write -> sA[nxt]; gload B(t+1) -> sB[nxt]
// Staging math bitwise identical to r6 (same cvtpk on same values, same B
// path) -> absmax provably unchanged. mfma operand order / fragments /
// epilogue verbatim from the proven kernel (operand swap = absmax 1.01,
// permanently banned). Revert criterion: gemm1 >= 46us or absmax change.
// LEDGER r9 (FAILED, 73us): A direct-from-global per k-step with NO prefetch
// distance = pure stall (MfmaUtil 6.7%). This kernel keeps LDS staging and
// adds the missing iteration of prefetch distance instead.
__global__ __launch_bounds__(256) void gemm1_pipe_kernel(
    const float* __restrict__ A, const u16* __restrict__ B,
    const float* __restrict__ bias, u16* __restrict__ C,
    int M, int N, int K) {
  __shared__ u16 sA[2][128 * 32];
  __shared__ u16 sB[2][128 * 32];
  const int tid = threadIdx.x;
  const int m0 = blockIdx.x * 128;
  const int n0 = blockIdx.y * 128;
  const int w = tid >> 6;
  const int lane = tid & 63;
  const int wr = (w >> 1) * 64;
  const int wc = (w & 1) * 64;
  const int lm = lane & 15;
  const int lk = (lane >> 4) * 8;

  f32x4 acc[4][4] = {};

  const int srow = tid >> 2;
  const int ssub = (tid & 3) * 8;
  const float* Agf = A + (size_t)(m0 + srow) * K + ssub;
  const u16* Bg = B + (size_t)(n0 + srow) * K + ssub;
  const size_t rstep = (size_t)64 * K;

  // prologue: stage tile 0 into buf 0
  {
    f32x4 p00 = *(const f32x4*)(Agf);
    f32x4 p01 = *(const f32x4*)(Agf + 4);
    f32x4 p10 = *(const f32x4*)(Agf + rstep);
    f32x4 p11 = *(const f32x4*)(Agf + rstep + 4);
    u32x4 w0, w1;
    w0[0] = cvtpk(p00[0], p00[1]); w0[1] = cvtpk(p00[2], p00[3]);
    w0[2] = cvtpk(p01[0], p01[1]); w0[3] = cvtpk(p01[2], p01[3]);
    w1[0] = cvtpk(p10[0], p10[1]); w1[1] = cvtpk(p10[2], p10[3]);
    w1[2] = cvtpk(p11[0], p11[1]); w1[3] = cvtpk(p11[2], p11[3]);
    *(u32x4*)&sA[0][tid * 8] = w0;
    *(u32x4*)&sA[0][2048 + tid * 8] = w1;
    lds_async16(Bg, &sB[0][tid * 8]);
    lds_async16(Bg + rstep, &sB[0][2048 + tid * 8]);
  }

  const int nt = K >> 5;
  for (int t = 0; t < nt; ++t) {
    const int cur = t & 1;
    const int nxt = cur ^ 1;
    __syncthreads();  // buf[cur] staged; prev iter's reads of buf[nxt] done
    const bool more = (t + 1 < nt);
    f32x4 n00, n01, n10, n11;
    if (more) {
      const int k1 = (t + 1) * 32;
      n00 = *(const f32x4*)(Agf + k1);
      n01 = *(const f32x4*)(Agf + k1 + 4);
      n10 = *(const f32x4*)(Agf + rstep + k1);
      n11 = *(const f32x4*)(Agf + rstep + k1 + 4);
    }
    bf16x8 af[4], bfr[4];
#pragma unroll
    for (int i = 0; i < 4; ++i)
      af[i] = *(const bf16x8*)&sA[cur][(wr + i * 16 + lm) * 32 + lk];
#pragma unroll
    for (int j = 0; j < 4; ++j)
      bfr[j] = *(const bf16x8*)&sB[cur][(wc + j * 16 + lm) * 32 + lk];
#pragma unroll
    for (int i = 0; i < 4; ++i)
#pragma unroll
      for (int j = 0; j < 4; ++j)
        acc[i][j] = __builtin_amdgcn_mfma_f32_16x16x32_bf16(af[i], bfr[j], acc[i][j], 0, 0, 0);
    if (more) {
      const int k1 = (t + 1) * 32;
      u32x4 w0, w1;
      w0[0] = cvtpk(n00[0], n00[1]); w0[1] = cvtpk(n00[2], n00[3]);
      w0[2] = cvtpk(n01[0], n01[1]); w0[3] = cvtpk(n01[2], n01[3]);
      w1[0] = cvtpk(n10[0], n10[1]); w1[1] = cvtpk(n10[2], n10[3]);
      w1[2] = cvtpk(n11[0], n11[1]); w1[3] = cvtpk(n11[2], n11[3]);
      *(u32x4*)&sA[nxt][tid * 8] = w0;
      *(u32x4*)&sA[nxt][2048 + tid * 8] = w1;
      lds_async16(Bg + k1, &sB[nxt][tid * 8]);
      lds_async16(Bg + rstep + k1, &sB[nxt][2048 + tid * 8]);
    }
  }

  const int r0 = (lane >> 4) * 4;
#pragma unroll
  for (int j = 0; j < 4; ++j) {
    const int n = n0 + wc + j * 16 + lm;
    const float bv = bias[n];
#pragma unroll
    for (int i = 0; i < 4; ++i) {
#pragma unroll
      for (int r = 0; r < 4; ++r) {
        const int m = m0 + wr + i * 16 + r0 + r;
        C[(size_t)m * N + n] = f2bf(acc[i][j][r] + bv);
      }
    }
  }
}

// ---------------- GEMM2 fused with overlap-add combine ----------------
// PROVEN r11 version (total 175.0us, absmax exact). y = combine(ows) @
// w_out^T + b_out without materializing oc. Block x: bc=x/33, ib=x%33
// block-uniform; two covering ows slabs are contiguous 128-row ranges.
// sc=0.5 is a power of two -> commutes exactly with bf16 rounding and MFMA;
// applied in the epilogue fmaf. Single-source blocks pass raw bf16 through.
// A-loads issued BEFORE the WAR barrier (r6 pattern). Do not swap mfma
// operand order.
__global__ __launch_bounds__(256) void gemm2_fused_kernel(
    const u16* __restrict__ ows, const u16* __restrict__ B,
    const float* __restrict__ bias, float* __restrict__ C,
    int M, int N, int K) {
  __shared__ u16 sA[128 * 32];
  __shared__ u16 sB[128 * 32];
  const int tid = threadIdx.x;
  const int x = blockIdx.x;
  const int m0 = x * 128;
  const int n0 = blockIdx.y * 128;
  const int bc = x / 33;
  const int ib = x - bc * 33;          // = i0, block-uniform
  const bool has0 = (ib <= 31);
  const bool has1 = (ib >= 1);
  const float sc = (has0 && has1) ? 0.5f : 1.0f;
  const int w = tid >> 6;
  const int lane = tid & 63;
  const int wr = (w >> 1) * 64;
  const int wc = (w & 1) * 64;
  const int lm = lane & 15;
  const int lk = (lane >> 4) * 8;

  f32x4 acc[4][4] = {};

  const int srow = tid >> 2;
  const int ssub = (tid & 3) * 8;
  const u16* A0 = ows + ((size_t)((bc * 32 + ib) * 256 + srow)) * 256 + ssub;
  const u16* A1 = ows + ((size_t)((bc * 32 + ib - 1) * 256 + 128 + srow)) * 256 + ssub;
  const size_t arstep = (size_t)64 * 256;
  const u16* Bg = B + (size_t)(n0 + srow) * K + ssub;
  const size_t rstep = (size_t)64 * K;

  for (int k0 = 0; k0 < K; k0 += 32) {
    u32x4 a00{}, a01{}, a10{}, a11{};
    // global loads issued before the barrier: overlap prev step's MFMAs
    if (has0) {
      a00 = *(const u32x4*)(A0 + k0);
      a01 = *(const u32x4*)(A0 + arstep + k0);
    }
    if (has1) {
      a10 = *(const u32x4*)(A1 + k0);
      a11 = *(const u32x4*)(A1 + arstep + k0);
    }
    __syncthreads();
    if (has0 && has1) {
      u32x4 w0, w1;
#pragma unroll
      for (int q = 0; q < 4; ++q) {
        float e0 = __builtin_bit_cast(float, a00[q] << 16) +
                   __builtin_bit_cast(float, a10[q] << 16);
        float o0 = __builtin_bit_cast(float, a00[q] & 0xFFFF0000u) +
                   __builtin_bit_cast(float, a10[q] & 0xFFFF0000u);
        w0[q] = cvtpk(e0, o0);
        float e1 = __builtin_bit_cast(float, a01[q] << 16) +
                   __builtin_bit_cast(float, a11[q] << 16);
        float o1 = __builtin_bit_cast(float, a01[q] & 0xFFFF0000u) +
                   __builtin_bit_cast(float, a11[q] & 0xFFFF0000u);
        w1[q] = cvtpk(e1, o1);
      }
      *(u32x4*)&sA[tid * 8] = w0;
      *(u32x4*)&sA[2048 + tid * 8] = w1;
    } else if (has0) {
      *(u32x4*)&sA[tid * 8] = a00;
      *(u32x4*)&sA[2048 + tid * 8] = a01;
    } else {
      *(u32x4*)&sA[tid * 8] = a10;
      *(u32x4*)&sA[2048 + tid * 8] = a11;
    }
    lds_async16(Bg + k0, &sB[tid * 8]);
    lds_async16(Bg + rstep + k0, &sB[2048 + tid * 8]);
    __syncthreads();
    bf16x8 af[4], bfr[4];
#pragma unroll
    for (int i = 0; i < 4; ++i)
      af[i] = *(const bf16x8*)&sA[(wr + i * 16 + lm) * 32 + lk];
#pragma unroll
    for (int j = 0; j < 4; ++j)
      bfr[j] = *(const bf16x8*)&sB[(wc + j * 16 + lm) * 32 + lk];
#pragma unroll
    for (int i = 0; i < 4; ++i)
#pragma unroll
      for (int j = 0; j < 4; ++j)
        acc[i][j] = __builtin_amdgcn_mfma_f32_16x16x32_bf16(af[i], bfr[j], acc[i][j], 0, 0, 0);
  }

  const int r0 = (lane >> 4) * 4;
#pragma unroll
  for (int j = 0; j < 4; ++j) {
    const int n = n0 + wc + j * 16 + lm;
    const float bv = bias[n];
#pragma unroll
    for (int i = 0; i < 4; ++i) {
#pragma unroll
      for (int r = 0; r < 4; ++r) {
        const int m = m0 + wr + i * 16 + r0 + r;
        C[(size_t)m * N + n] = __builtin_fmaf(sc, acc[i][j][r], bv);
      }
    }
  }
}

// ---------------- fused per-(block,head) attention ----------------
// ROUND-2 EXACT SOURCE (proven 44.3-45.2us, VGPR 64). Do not "improve"
// without a within-session A/B.
// LEDGER (measured):
//  r2 44.9us: sVt col XOR-swizzle; cvt_pk packing; denominator via
//    mfma(P, ones); 1-deep K prefetch; setprio; single sP + WAR fence.
//  r3 48.0us REGRESSED: sP hf-dbuf + V-reg-prefetch -> VGPR 68 crossed the
//    64-VGPR allocation cliff (8->7 waves/SIMD), occ 31->24%.
//  r4 48.0us: sP-XOR changed conflict count by exactly 0 -> conflicts are
//    NOT sP; V-prefetch's +4 VGPR was the whole r3 regression.
//    LESSON: stay at VGPR <= 64.
//  r5 FAILED (absmax 0.19): K-row re-tiling to keep PV A-fragment in regs.
//    OPEN MYSTERY — do not retry without disasm evidence.
// launch_bounds(256,2): (256,4) spilled catastrophically. `#pragma unroll 1`
// on the ch loop is load-bearing: full unroll hoists all kf loads and spills.
// The asm memory fence pins the P-tile read -> overwrite (WAR) order.
__global__ __launch_bounds__(256, 2) void attn_kernel(const u16* __restrict__ qkv,
                                                      u16* __restrict__ o_ws) {
  __shared__ u16 sVt[32 * 264];   // V transposed, stride 264 u16, cols XOR-swizzled
  __shared__ u16 sP[4 * 32 * 40]; // per-wave P half-tile: 32 rows x 40 u16

  const int bid = blockIdx.x;
  const int n = bid >> 3;
  const int h = bid & 7;
  const int rowbase = (n >> 5) * 4224 + (n & 31) * 128;
  const int tid = threadIdx.x;
  const int w = tid >> 6;
  const int lane = tid & 63;
  const int lm = lane & 15;
  const int lg = lane >> 4;

  // stage V transposed for this head: V[j][d] -> sVt[d*264 + (j ^ ((d>>3)<<4))]
#pragma unroll
  for (int it = 0; it < 4; ++it) {
    int c = it * 256 + tid;
    int row = c >> 2;
    int sub = (c & 3) * 8;
    int rsw = row ^ ((sub >> 3) << 4);   // swizzled column; (d>>3) is sub>>3 for all 8 d
    const u16* gv = qkv + (size_t)(rowbase + row) * 768 + 512 + h * 32 + sub;
    u32x4 vv = *(const u32x4*)gv;
#pragma unroll
    for (int q = 0; q < 4; ++q) {
      sVt[(sub + 2 * q) * 264 + rsw] = (u16)(vv[q] & 0xFFFFu);
      sVt[(sub + 2 * q + 1) * 264 + rsw] = (u16)(vv[q] >> 16);
    }
  }

  // Q fragments straight from global (wave-private rows; 16 rows x 64B contiguous)
  bf16x8 qf[4];
#pragma unroll
  for (int rt = 0; rt < 4; ++rt) {
    int row = rowbase + w * 64 + rt * 16 + lm;
    qf[rt] = *(const bf16x8*)(qkv + (size_t)row * 768 + h * 32 + lg * 8);
  }

  const u16* kbase = qkv + (size_t)(rowbase + lm) * 768 + 256 + h * 32 + lg * 8;

  // prime K prefetch for ch=0 (overlaps the staging barrier)
  bf16x8 kfc[2];
#pragma unroll
  for (int ct = 0; ct < 2; ++ct)
    kfc[ct] = *(const bf16x8*)(kbase + (size_t)(ct * 16) * 768);

  __syncthreads();

  f32x4 oacc[4][2] = {};
  f32x4 lacc[4] = {};   // softmax denominators via mfma(P, ones)
  u16* myP = sP + w * (32 * 40);
  const float C1 = 0.25500035370494726f; // scale * log2(e)
  const float C2 = 1.4426950408889634f;  // log2(e)
  const int jq = lg * 4;
  const int D0w = w * 64;
  const bf16x8 onesb = {(short)0x3F80, (short)0x3F80, (short)0x3F80, (short)0x3F80,
                        (short)0x3F80, (short)0x3F80, (short)0x3F80, (short)0x3F80};

#pragma unroll 1
  for (int ch = 0; ch < 8; ++ch) {
    // prefetch next chunk's K fragments (clamped; last iter loads are dead)
    const int chn = (ch < 7) ? ch + 1 : 7;
    bf16x8 kfn[2], vf[2];
#pragma unroll
    for (int ct = 0; ct < 2; ++ct)
      kfn[ct] = *(const bf16x8*)(kbase + (size_t)(chn * 32 + ct * 16) * 768);
#pragma unroll
    for (int ctd = 0; ctd < 2; ++ctd) {
      int d = ctd * 16 + lm;
      vf[ctd] = *(const bf16x8*)&sVt[d * 264 + ((ch * 32 + lg * 8) ^ ((d >> 3) << 4))];
    }

#pragma unroll
    for (int hf = 0; hf < 2; ++hf) {
#pragma unroll
      for (int ct = 0; ct < 2; ++ct) {
#pragma unroll
        for (int rl = 0; rl < 2; ++rl) {
          const int rt = hf * 2 + rl;
          f32x4 s = __builtin_amdgcn_mfma_f32_16x16x32_bf16(kfc[ct], qf[rt], f32x4{0.f, 0.f, 0.f, 0.f}, 0, 0, 0);
          const int D0 = D0w + rt * 16 - (ch * 32 + ct * 16); // wave-uniform
          float p0, p1, p2, p3;
          if (D0 >= 16 && D0 <= 112) {        // fully in-band: +1 bias
            p0 = fexp2(__builtin_fmaf(s[0], C1, C2));
            p1 = fexp2(__builtin_fmaf(s[1], C1, C2));
            p2 = fexp2(__builtin_fmaf(s[2], C1, C2));
            p3 = fexp2(__builtin_fmaf(s[3], C1, C2));
          } else if (D0 == 0) {               // diagonal: in-band iff lm >= jq+r
            p0 = fexp2(__builtin_fmaf(s[0], C1, (lm >= jq + 0) ? C2 : 0.0f));
            p1 = fexp2(__builtin_fmaf(s[1], C1, (lm >= jq + 1) ? C2 : 0.0f));
            p2 = fexp2(__builtin_fmaf(s[2], C1, (lm >= jq + 2) ? C2 : 0.0f));
            p3 = fexp2(__builtin_fmaf(s[3], C1, (lm >= jq + 3) ? C2 : 0.0f));
          } else if (D0 == 128) {             // far edge: in-band iff lm < jq+r
            p0 = fexp2(__builtin_fmaf(s[0], C1, (lm < jq + 0) ? C2 : 0.0f));
            p1 = fexp2(__builtin_fmaf(s[1], C1, (lm < jq + 1) ? C2 : 0.0f));
            p2 = fexp2(__builtin_fmaf(s[2], C1, (lm < jq + 2) ? C2 : 0.0f));
            p3 = fexp2(__builtin_fmaf(s[3], C1, (lm < jq + 3) ? C2 : 0.0f));
          } else {                            // fully out of band: no bias
            p0 = fexp2(s[0] * C1);
            p1 = fexp2(s[1] * C1);
            p2 = fexp2(s[2] * C1);
            p3 = fexp2(s[3] * C1);
          }
          u32 a0, a1;
          asm("v_cvt_pk_bf16_f32 %0, %1, %2" : "=v"(a0) : "v"(p0), "v"(p1));
          asm("v_cvt_pk_bf16_f32 %0, %1, %2" : "=v"(a1) : "v"(p2), "v"(p3));
          u32x2 pk;
          pk[0] = a0;
          pk[1] = a1;
          *(u32x2*)&myP[(rl * 16 + lm) * 40 + ct * 16 + jq] = pk;
        }
      }
      // O(half) += P(half) * Vc ; lsum(half) += P(half) . 1  (wave-private P)
      bf16x8 pf[2];
#pragma unroll
      for (int rl = 0; rl < 2; ++rl)
        pf[rl] = *(const bf16x8*)&myP[(rl * 16 + lm) * 40 + lg * 8];
      // pin WAR order: these reads must precede the next half's overwrites
      __asm__ __volatile__("" ::: "memory");
      __builtin_amdgcn_s_setprio(1);
#pragma unroll
      for (int rl = 0; rl < 2; ++rl) {
        lacc[hf * 2 + rl] =
            __builtin_amdgcn_mfma_f32_16x16x32_bf16(pf[rl], onesb, lacc[hf * 2 + rl], 0, 0, 0);
#pragma unroll
        for (int ctd = 0; ctd < 2; ++ctd)
          oacc[hf * 2 + rl][ctd] =
              __builtin_amdgcn_mfma_f32_16x16x32_bf16(pf[rl], vf[ctd], oacc[hf * 2 + rl][ctd], 0, 0, 0);
      }
      __builtin_amdgcn_s_setprio(0);
    }
    kfc[0] = kfn[0];
    kfc[1] = kfn[1];
  }

  // normalize + store; lacc[rt][r] holds the full denominator for row
  // i = rt*16 + lg*4 + r (C/D layout row = lg*4+r), exactly the epilogue row.
#pragma unroll
  for (int rt = 0; rt < 4; ++rt) {
#pragma unroll
    for (int r = 0; r < 4; ++r) {
      float inv = 1.0f / lacc[rt][r];
      int i_g = w * 64 + rt * 16 + jq + r;
#pragma unroll
      for (int ctd = 0; ctd < 2; ++ctd) {
        float v = oacc[rt][ctd][r] * inv;
        u32 u = __builtin_bit_cast(u32, v) + 0x8000u;
        o_ws[((size_t)(n * 256 + i_g)) * 256 + h * 32 + ctd * 16 + lm] = (u16)(u >> 16);
      }
    }
  }
}

extern "C" void kernel_launch(void* const* d_in, const int* in_sizes, int n_in,
                              void* d_out, int out_size, void* d_ws, size_t ws_size,
                              hipStream_t stream) {
  const float* x = (const float*)d_in[0];
  const float* w_in = (const float*)d_in[1];
  const float* b_in = (const float*)d_in[2];
  const float* w_out = (const float*)d_in[3];
  const float* b_out = (const float*)d_in[4];
  float* y = (float*)d_out;
  char* ws = (char*)d_ws;

  // workspace layout (bytes)
  u16* qkv = (u16*)(ws);                   // 33792*768*2   = 51,904,512
  u16* ows = (u16*)(ws + 69206016);        // 256*256*256*2 = 33,554,432
  u16* winb = (u16*)(ws + 102760448);      // 768*256*2     = 393,216
  u16* woutb = (u16*)(ws + 103153664);     // 256*256*2     = 131,072  (end 103,284,736)

  cvt2_kernel<<<256, 256, 0, stream>>>(w_in, w_out, winb, woutb, 49152, 16384);

  // qkv = x @ w_in^T + b_in — pipelined: A f32 reg-prefetch + sA/sB dbuf,
  // one barrier per k-step
  gemm1_pipe_kernel<<<dim3(264, 6), 256, 0, stream>>>(x, winb, b_in, qkv, 33792, 768, 256);

  // per-(block, head) attention
  attn_kernel<<<2048, 256, 0, stream>>>(qkv, ows);

  // y = combine(ows) @ w_out^T + b_out — overlap-add fused into A-staging
  gemm2_fused_kernel<<<dim3(264, 2), 256, 0, stream>>>(ows, woutb, b_out, y, 33792, 256, 256);
}

// Round 13
// 168.466 us; speedup vs baseline: 1.2357x; 1.0023x over previous
//
#include <hip/hip_runtime.h>

typedef unsigned short u16;
typedef unsigned int u32;
typedef __attribute__((ext_vector_type(8))) short bf16x8;
typedef __attribute__((ext_vector_type(4))) float f32x4;
typedef __attribute__((ext_vector_type(4))) u32 u32x4;
typedef __attribute__((ext_vector_type(2))) u32 u32x2;

__device__ __forceinline__ u16 f2bf(float f) {
  u32 u = __builtin_bit_cast(u32, f);
  return (u16)((u + 0x7FFFu + ((u >> 16) & 1u)) >> 16);
}
__device__ __forceinline__ float bf2f(u16 b) {
  return __builtin_bit_cast(float, (u32)b << 16);
}

// v_cvt_pk_bf16_f32 = RNE, bitwise-identical to f2bf for finite inputs
// (proven: r6 fused gemm1 kept absmax exactly 0.001953125).
__device__ __forceinline__ u32 cvtpk(float lo, float hi) {
  u32 r;
  asm("v_cvt_pk_bf16_f32 %0, %1, %2" : "=v"(r) : "v"(lo), "v"(hi));
  return r;
}

__device__ __forceinline__ float fexp2(float x) {
#if __has_builtin(__builtin_amdgcn_exp2f)
  return __builtin_amdgcn_exp2f(x);
#else
  return __expf(x * 0.6931471805599453f);
#endif
}

__device__ __forceinline__ void lds_async16(const void* g, void* l) {
  auto gp = reinterpret_cast<const __attribute__((address_space(1))) u32*>(
      reinterpret_cast<uintptr_t>(g));
  auto lp = reinterpret_cast<__attribute__((address_space(3))) u32*>(
      reinterpret_cast<uintptr_t>(l));
  __builtin_amdgcn_global_load_lds(gp, lp, 16, 0, 0);
}

// combine two ows slabs into packed bf16 (overlap-add); bitwise identical to
// the old combine_kernel + gemm path (sc folded into the gemm epilogue).
__device__ __forceinline__ u32x4 combine_pair(u32x4 a0, u32x4 a1, bool has0, bool has1) {
  if (has0 && has1) {
    u32x4 w;
#pragma unroll
    for (int q = 0; q < 4; ++q) {
      float e = __builtin_bit_cast(float, a0[q] << 16) +
                __builtin_bit_cast(float, a1[q] << 16);
      float o = __builtin_bit_cast(float, a0[q] & 0xFFFF0000u) +
                __builtin_bit_cast(float, a1[q] & 0xFFFF0000u);
      w[q] = cvtpk(e, o);
    }
    return w;
  }
  return has0 ? a0 : a1;
}

// two small weight converts in one launch
__global__ void cvt2_kernel(const float* __restrict__ a, const float* __restrict__ b,
                            u16* __restrict__ oa, u16* __restrict__ ob, int na4, int nb4) {
  int i = blockIdx.x * 256 + threadIdx.x;
  const float* src;
  u16* dst;
  int idx;
  if (i < na4) {
    src = a; dst = oa; idx = i;
  } else {
    idx = i - na4;
    if (idx >= nb4) return;
    src = b; dst = ob;
  }
  f32x4 v = *(const f32x4*)(src + (size_t)idx * 4);
  u32x2 o;
  o[0] = (u32)f2bf(v[0]) | ((u32)f2bf(v[1]) << 16);
  o[1] = (u32)f2bf(v[2]) | ((u32)f2bf(v[3]) << 16);
  *(u32x2*)(dst + (size_t)idx * 4) = o;
}

// ---------------- GEMM1 pipelined: qkv = x @ w_in^T + b_in, bf16 out --------
// PROVEN r12 version (gemm1 46.3 -> ~40us, total 168.9, absmax exact).
// Single barrier per k-step, sA/sB double-buffered (32KB). Iteration t:
//   barrier -> issue A(t+1) f32 reg-loads -> ds_read + 16 MFMA on buf[cur]
//   -> cvt A(t+1)+ds_write, gload B(t+1) into buf[nxt].
// LEDGER r9 (FAILED, 73us): A direct-from-global with NO prefetch distance =
// pure stall (MfmaUtil 6.7%). Prefetch DISTANCE is the lever, not LDS removal.
// Operand swap mfma(bfr, af) produced absmax 1.01 — permanently banned.
__global__ __launch_bounds__(256) void gemm1_pipe_kernel(
    const float* __restrict__ A, const u16* __restrict__ B,
    const float* __restrict__ bias, u16* __restrict__ C,
    int M, int N, int K) {
  __shared__ u16 sA[2][128 * 32];
  __shared__ u16 sB[2][128 * 32];
  const int tid = threadIdx.x;
  const int m0 = blockIdx.x * 128;
  const int n0 = blockIdx.y * 128;
  const int w = tid >> 6;
  const int lane = tid & 63;
  const int wr = (w >> 1) * 64;
  const int wc = (w & 1) * 64;
  const int lm = lane & 15;
  const int lk = (lane >> 4) * 8;

  f32x4 acc[4][4] = {};

  const int srow = tid >> 2;
  const int ssub = (tid & 3) * 8;
  const float* Agf = A + (size_t)(m0 + srow) * K + ssub;
  const u16* Bg = B + (size_t)(n0 + srow) * K + ssub;
  const size_t rstep = (size_t)64 * K;

  // prologue: stage tile 0 into buf 0
  {
    f32x4 p00 = *(const f32x4*)(Agf);
    f32x4 p01 = *(const f32x4*)(Agf + 4);
    f32x4 p10 = *(const f32x4*)(Agf + rstep);
    f32x4 p11 = *(const f32x4*)(Agf + rstep + 4);
    u32x4 w0, w1;
    w0[0] = cvtpk(p00[0], p00[1]); w0[1] = cvtpk(p00[2], p00[3]);
    w0[2] = cvtpk(p01[0], p01[1]); w0[3] = cvtpk(p01[2], p01[3]);
    w1[0] = cvtpk(p10[0], p10[1]); w1[1] = cvtpk(p10[2], p10[3]);
    w1[2] = cvtpk(p11[0], p11[1]); w1[3] = cvtpk(p11[2], p11[3]);
    *(u32x4*)&sA[0][tid * 8] = w0;
    *(u32x4*)&sA[0][2048 + tid * 8] = w1;
    lds_async16(Bg, &sB[0][tid * 8]);
    lds_async16(Bg + rstep, &sB[0][2048 + tid * 8]);
  }

  const int nt = K >> 5;
  for (int t = 0; t < nt; ++t) {
    const int cur = t & 1;
    const int nxt = cur ^ 1;
    __syncthreads();  // buf[cur] staged; prev iter's reads of buf[nxt] done
    const bool more = (t + 1 < nt);
    f32x4 n00, n01, n10, n11;
    if (more) {
      const int k1 = (t + 1) * 32;
      n00 = *(const f32x4*)(Agf + k1);
      n01 = *(const f32x4*)(Agf + k1 + 4);
      n10 = *(const f32x4*)(Agf + rstep + k1);
      n11 = *(const f32x4*)(Agf + rstep + k1 + 4);
    }
    bf16x8 af[4], bfr[4];
#pragma unroll
    for (int i = 0; i < 4; ++i)
      af[i] = *(const bf16x8*)&sA[cur][(wr + i * 16 + lm) * 32 + lk];
#pragma unroll
    for (int j = 0; j < 4; ++j)
      bfr[j] = *(const bf16x8*)&sB[cur][(wc + j * 16 + lm) * 32 + lk];
#pragma unroll
    for (int i = 0; i < 4; ++i)
#pragma unroll
      for (int j = 0; j < 4; ++j)
        acc[i][j] = __builtin_amdgcn_mfma_f32_16x16x32_bf16(af[i], bfr[j], acc[i][j], 0, 0, 0);
    if (more) {
      const int k1 = (t + 1) * 32;
      u32x4 w0, w1;
      w0[0] = cvtpk(n00[0], n00[1]); w0[1] = cvtpk(n00[2], n00[3]);
      w0[2] = cvtpk(n01[0], n01[1]); w0[3] = cvtpk(n01[2], n01[3]);
      w1[0] = cvtpk(n10[0], n10[1]); w1[1] = cvtpk(n10[2], n10[3]);
      w1[2] = cvtpk(n11[0], n11[1]); w1[3] = cvtpk(n11[2], n11[3]);
      *(u32x4*)&sA[nxt][tid * 8] = w0;
      *(u32x4*)&sA[nxt][2048 + tid * 8] = w1;
      lds_async16(Bg + k1, &sB[nxt][tid * 8]);
      lds_async16(Bg + rstep + k1, &sB[nxt][2048 + tid * 8]);
    }
  }

  const int r0 = (lane >> 4) * 4;
#pragma unroll
  for (int j = 0; j < 4; ++j) {
    const int n = n0 + wc + j * 16 + lm;
    const float bv = bias[n];
#pragma unroll
    for (int i = 0; i < 4; ++i) {
#pragma unroll
      for (int r = 0; r < 4; ++r) {
        const int m = m0 + wr + i * 16 + r0 + r;
        C[(size_t)m * N + n] = f2bf(acc[i][j][r] + bv);
      }
    }
  }
}

// ---------------- GEMM2 fused+pipelined: y = combine(ows) @ w_out^T + b_out --
// Round-13: r11's combine-fusion (proven bitwise-exact) + r12's proven
// single-barrier dbuf pipeline. Block x: bc=x/33, ib=x%33 block-uniform;
// the two covering ows slabs are contiguous 128-row ranges. sc=0.5 is a
// power of two -> commutes with bf16 rounding and MFMA; applied in the
// epilogue fmaf. Iteration t: barrier -> issue A(t+1) slab reg-loads ->
// ds_read + 16 MFMA on buf[cur] -> combine A(t+1) + ds_write, gload B(t+1)
// into buf[nxt]. Staging math identical to r11 -> absmax unchanged.
// Do not swap mfma operand order.
__global__ __launch_bounds__(256) void gemm2_pipe_kernel(
    const u16* __restrict__ ows, const u16* __restrict__ B,
    const float* __restrict__ bias, float* __restrict__ C,
    int M, int N, int K) {
  __shared__ u16 sA[2][128 * 32];
  __shared__ u16 sB[2][128 * 32];
  const int tid = threadIdx.x;
  const int x = blockIdx.x;
  const int m0 = x * 128;
  const int n0 = blockIdx.y * 128;
  const int bc = x / 33;
  const int ib = x - bc * 33;          // = i0, block-uniform
  const bool has0 = (ib <= 31);
  const bool has1 = (ib >= 1);
  const float sc = (has0 && has1) ? 0.5f : 1.0f;
  const int w = tid >> 6;
  const int lane = tid & 63;
  const int wr = (w >> 1) * 64;
  const int wc = (w & 1) * 64;
  const int lm = lane & 15;
  const int lk = (lane >> 4) * 8;

  f32x4 acc[4][4] = {};

  const int srow = tid >> 2;
  const int ssub = (tid & 3) * 8;
  const u16* A0 = ows + ((size_t)((bc * 32 + ib) * 256 + srow)) * 256 + ssub;
  const u16* A1 = ows + ((size_t)((bc * 32 + ib - 1) * 256 + 128 + srow)) * 256 + ssub;
  const size_t arstep = (size_t)64 * 256;
  const u16* Bg = B + (size_t)(n0 + srow) * K + ssub;
  const size_t rstep = (size_t)64 * K;

  // prologue: stage tile 0 into buf 0
  {
    u32x4 a00{}, a01{}, a10{}, a11{};
    if (has0) {
      a00 = *(const u32x4*)(A0);
      a01 = *(const u32x4*)(A0 + arstep);
    }
    if (has1) {
      a10 = *(const u32x4*)(A1);
      a11 = *(const u32x4*)(A1 + arstep);
    }
    *(u32x4*)&sA[0][tid * 8] = combine_pair(a00, a10, has0, has1);
    *(u32x4*)&sA[0][2048 + tid * 8] = combine_pair(a01, a11, has0, has1);
    lds_async16(Bg, &sB[0][tid * 8]);
    lds_async16(Bg + rstep, &sB[0][2048 + tid * 8]);
  }

  const int nt = K >> 5;
  for (int t = 0; t < nt; ++t) {
    const int cur = t & 1;
    const int nxt = cur ^ 1;
    __syncthreads();  // buf[cur] staged; prev iter's reads of buf[nxt] done
    const bool more = (t + 1 < nt);
    u32x4 n00{}, n01{}, n10{}, n11{};
    if (more) {
      const int k1 = (t + 1) * 32;
      if (has0) {
        n00 = *(const u32x4*)(A0 + k1);
        n01 = *(const u32x4*)(A0 + arstep + k1);
      }
      if (has1) {
        n10 = *(const u32x4*)(A1 + k1);
        n11 = *(const u32x4*)(A1 + arstep + k1);
      }
    }
    bf16x8 af[4], bfr[4];
#pragma unroll
    for (int i = 0; i < 4; ++i)
      af[i] = *(const bf16x8*)&sA[cur][(wr + i * 16 + lm) * 32 + lk];
#pragma unroll
    for (int j = 0; j < 4; ++j)
      bfr[j] = *(const bf16x8*)&sB[cur][(wc + j * 16 + lm) * 32 + lk];
#pragma unroll
    for (int i = 0; i < 4; ++i)
#pragma unroll
      for (int j = 0; j < 4; ++j)
        acc[i][j] = __builtin_amdgcn_mfma_f32_16x16x32_bf16(af[i], bfr[j], acc[i][j], 0, 0, 0);
    if (more) {
      const int k1 = (t + 1) * 32;
      *(u32x4*)&sA[nxt][tid * 8] = combine_pair(n00, n10, has0, has1);
      *(u32x4*)&sA[nxt][2048 + tid * 8] = combine_pair(n01, n11, has0, has1);
      lds_async16(Bg + k1, &sB[nxt][tid * 8]);
      lds_async16(Bg + rstep + k1, &sB[nxt][2048 + tid * 8]);
    }
  }

  const int r0 = (lane >> 4) * 4;
#pragma unroll
  for (int j = 0; j < 4; ++j) {
    const int n = n0 + wc + j * 16 + lm;
    const float bv = bias[n];
#pragma unroll
    for (int i = 0; i < 4; ++i) {
#pragma unroll
      for (int r = 0; r < 4; ++r) {
        const int m = m0 + wr + i * 16 + r0 + r;
        C[(size_t)m * N + n] = __builtin_fmaf(sc, acc[i][j][r], bv);
      }
    }
  }
}

// ---------------- fused per-(block,head) attention ----------------
// ROUND-2 EXACT SOURCE (proven 44.3-45.2us, VGPR 64). Do not "improve"
// without a within-session A/B.
// LEDGER (measured):
//  r2 44.9us: sVt col XOR-swizzle; cvt_pk packing; denominator via
//    mfma(P, ones); 1-deep K prefetch; setprio; single sP + WAR fence.
//  r3 48.0us REGRESSED: sP hf-dbuf + V-reg-prefetch -> VGPR 68 crossed the
//    64-VGPR allocation cliff (8->7 waves/SIMD), occ 31->24%.
//  r4 48.0us: sP-XOR changed conflict count by exactly 0 -> conflicts are
//    NOT sP; V-prefetch's +4 VGPR was the whole r3 regression.
//    LESSON: stay at VGPR <= 64.
//  r5 FAILED (absmax 0.19): K-row re-tiling to keep PV A-fragment in regs.
//    OPEN MYSTERY — do not retry without disasm evidence.
// launch_bounds(256,2): (256,4) spilled catastrophically. `#pragma unroll 1`
// on the ch loop is load-bearing: full unroll hoists all kf loads and spills.
// The asm memory fence pins the P-tile read -> overwrite (WAR) order.
__global__ __launch_bounds__(256, 2) void attn_kernel(const u16* __restrict__ qkv,
                                                      u16* __restrict__ o_ws) {
  __shared__ u16 sVt[32 * 264];   // V transposed, stride 264 u16, cols XOR-swizzled
  __shared__ u16 sP[4 * 32 * 40]; // per-wave P half-tile: 32 rows x 40 u16

  const int bid = blockIdx.x;
  const int n = bid >> 3;
  const int h = bid & 7;
  const int rowbase = (n >> 5) * 4224 + (n & 31) * 128;
  const int tid = threadIdx.x;
  const int w = tid >> 6;
  const int lane = tid & 63;
  const int lm = lane & 15;
  const int lg = lane >> 4;

  // stage V transposed for this head: V[j][d] -> sVt[d*264 + (j ^ ((d>>3)<<4))]
#pragma unroll
  for (int it = 0; it < 4; ++it) {
    int c = it * 256 + tid;
    int row = c >> 2;
    int sub = (c & 3) * 8;
    int rsw = row ^ ((sub >> 3) << 4);   // swizzled column; (d>>3) is sub>>3 for all 8 d
    const u16* gv = qkv + (size_t)(rowbase + row) * 768 + 512 + h * 32 + sub;
    u32x4 vv = *(const u32x4*)gv;
#pragma unroll
    for (int q = 0; q < 4; ++q) {
      sVt[(sub + 2 * q) * 264 + rsw] = (u16)(vv[q] & 0xFFFFu);
      sVt[(sub + 2 * q + 1) * 264 + rsw] = (u16)(vv[q] >> 16);
    }
  }

  // Q fragments straight from global (wave-private rows; 16 rows x 64B contiguous)
  bf16x8 qf[4];
#pragma unroll
  for (int rt = 0; rt < 4; ++rt) {
    int row = rowbase + w * 64 + rt * 16 + lm;
    qf[rt] = *(const bf16x8*)(qkv + (size_t)row * 768 + h * 32 + lg * 8);
  }

  const u16* kbase = qkv + (size_t)(rowbase + lm) * 768 + 256 + h * 32 + lg * 8;

  // prime K prefetch for ch=0 (overlaps the staging barrier)
  bf16x8 kfc[2];
#pragma unroll
  for (int ct = 0; ct < 2; ++ct)
    kfc[ct] = *(const bf16x8*)(kbase + (size_t)(ct * 16) * 768);

  __syncthreads();

  f32x4 oacc[4][2] = {};
  f32x4 lacc[4] = {};   // softmax denominators via mfma(P, ones)
  u16* myP = sP + w * (32 * 40);
  const float C1 = 0.25500035370494726f; // scale * log2(e)
  const float C2 = 1.4426950408889634f;  // log2(e)
  const int jq = lg * 4;
  const int D0w = w * 64;
  const bf16x8 onesb = {(short)0x3F80, (short)0x3F80, (short)0x3F80, (short)0x3F80,
                        (short)0x3F80, (short)0x3F80, (short)0x3F80, (short)0x3F80};

#pragma unroll 1
  for (int ch = 0; ch < 8; ++ch) {
    // prefetch next chunk's K fragments (clamped; last iter loads are dead)
    const int chn = (ch < 7) ? ch + 1 : 7;
    bf16x8 kfn[2], vf[2];
#pragma unroll
    for (int ct = 0; ct < 2; ++ct)
      kfn[ct] = *(const bf16x8*)(kbase + (size_t)(chn * 32 + ct * 16) * 768);
#pragma unroll
    for (int ctd = 0; ctd < 2; ++ctd) {
      int d = ctd * 16 + lm;
      vf[ctd] = *(const bf16x8*)&sVt[d * 264 + ((ch * 32 + lg * 8) ^ ((d >> 3) << 4))];
    }

#pragma unroll
    for (int hf = 0; hf < 2; ++hf) {
#pragma unroll
      for (int ct = 0; ct < 2; ++ct) {
#pragma unroll
        for (int rl = 0; rl < 2; ++rl) {
          const int rt = hf * 2 + rl;
          f32x4 s = __builtin_amdgcn_mfma_f32_16x16x32_bf16(kfc[ct], qf[rt], f32x4{0.f, 0.f, 0.f, 0.f}, 0, 0, 0);
          const int D0 = D0w + rt * 16 - (ch * 32 + ct * 16); // wave-uniform
          float p0, p1, p2, p3;
          if (D0 >= 16 && D0 <= 112) {        // fully in-band: +1 bias
            p0 = fexp2(__builtin_fmaf(s[0], C1, C2));
            p1 = fexp2(__builtin_fmaf(s[1], C1, C2));
            p2 = fexp2(__builtin_fmaf(s[2], C1, C2));
            p3 = fexp2(__builtin_fmaf(s[3], C1, C2));
          } else if (D0 == 0) {               // diagonal: in-band iff lm >= jq+r
            p0 = fexp2(__builtin_fmaf(s[0], C1, (lm >= jq + 0) ? C2 : 0.0f));
            p1 = fexp2(__builtin_fmaf(s[1], C1, (lm >= jq + 1) ? C2 : 0.0f));
            p2 = fexp2(__builtin_fmaf(s[2], C1, (lm >= jq + 2) ? C2 : 0.0f));
            p3 = fexp2(__builtin_fmaf(s[3], C1, (lm >= jq + 3) ? C2 : 0.0f));
          } else if (D0 == 128) {             // far edge: in-band iff lm < jq+r
            p0 = fexp2(__builtin_fmaf(s[0], C1, (lm < jq + 0) ? C2 : 0.0f));
            p1 = fexp2(__builtin_fmaf(s[1], C1, (lm < jq + 1) ? C2 : 0.0f));
            p2 = fexp2(__builtin_fmaf(s[2], C1, (lm < jq + 2) ? C2 : 0.0f));
            p3 = fexp2(__builtin_fmaf(s[3], C1, (lm < jq + 3) ? C2 : 0.0f));
          } else {                            // fully out of band: no bias
            p0 = fexp2(s[0] * C1);
            p1 = fexp2(s[1] * C1);
            p2 = fexp2(s[2] * C1);
            p3 = fexp2(s[3] * C1);
          }
          u32 a0, a1;
          asm("v_cvt_pk_bf16_f32 %0, %1, %2" : "=v"(a0) : "v"(p0), "v"(p1));
          asm("v_cvt_pk_bf16_f32 %0, %1, %2" : "=v"(a1) : "v"(p2), "v"(p3));
          u32x2 pk;
          pk[0] = a0;
          pk[1] = a1;
          *(u32x2*)&myP[(rl * 16 + lm) * 40 + ct * 16 + jq] = pk;
        }
      }
      // O(half) += P(half) * Vc ; lsum(half) += P(half) . 1  (wave-private P)
      bf16x8 pf[2];
#pragma unroll
      for (int rl = 0; rl < 2; ++rl)
        pf[rl] = *(const bf16x8*)&myP[(rl * 16 + lm) * 40 + lg * 8];
      // pin WAR order: these reads must precede the next half's overwrites
      __asm__ __volatile__("" ::: "memory");
      __builtin_amdgcn_s_setprio(1);
#pragma unroll
      for (int rl = 0; rl < 2; ++rl) {
        lacc[hf * 2 + rl] =
            __builtin_amdgcn_mfma_f32_16x16x32_bf16(pf[rl], onesb, lacc[hf * 2 + rl], 0, 0, 0);
#pragma unroll
        for (int ctd = 0; ctd < 2; ++ctd)
          oacc[hf * 2 + rl][ctd] =
              __builtin_amdgcn_mfma_f32_16x16x32_bf16(pf[rl], vf[ctd], oacc[hf * 2 + rl][ctd], 0, 0, 0);
      }
      __builtin_amdgcn_s_setprio(0);
    }
    kfc[0] = kfn[0];
    kfc[1] = kfn[1];
  }

  // normalize + store; lacc[rt][r] holds the full denominator for row
  // i = rt*16 + lg*4 + r (C/D layout row = lg*4+r), exactly the epilogue row.
#pragma unroll
  for (int rt = 0; rt < 4; ++rt) {
#pragma unroll
    for (int r = 0; r < 4; ++r) {
      float inv = 1.0f / lacc[rt][r];
      int i_g = w * 64 + rt * 16 + jq + r;
#pragma unroll
      for (int ctd = 0; ctd < 2; ++ctd) {
        float v = oacc[rt][ctd][r] * inv;
        u32 u = __builtin_bit_cast(u32, v) + 0x8000u;
        o_ws[((size_t)(n * 256 + i_g)) * 256 + h * 32 + ctd * 16 + lm] = (u16)(u >> 16);
      }
    }
  }
}

extern "C" void kernel_launch(void* const* d_in, const int* in_sizes, int n_in,
                              void* d_out, int out_size, void* d_ws, size_t ws_size,
                              hipStream_t stream) {
  const float* x = (const float*)d_in[0];
  const float* w_in = (const float*)d_in[1];
  const float* b_in = (const float*)d_in[2];
  const float* w_out = (const float*)d_in[3];
  const float* b_out = (const float*)d_in[4];
  float* y = (float*)d_out;
  char* ws = (char*)d_ws;

  // workspace layout (bytes)
  u16* qkv = (u16*)(ws);                   // 33792*768*2   = 51,904,512
  u16* ows = (u16*)(ws + 69206016);        // 256*256*256*2 = 33,554,432
  u16* winb = (u16*)(ws + 102760448);      // 768*256*2     = 393,216
  u16* woutb = (u16*)(ws + 103153664);     // 256*256*2     = 131,072  (end 103,284,736)

  cvt2_kernel<<<256, 256, 0, stream>>>(w_in, w_out, winb, woutb, 49152, 16384);

  // qkv = x @ w_in^T + b_in — pipelined: A f32 reg-prefetch + sA/sB dbuf,
  // one barrier per k-step
  gemm1_pipe_kernel<<<dim3(264, 6), 256, 0, stream>>>(x, winb, b_in, qkv, 33792, 768, 256);

  // per-(block, head) attention
  attn_kernel<<<2048, 256, 0, stream>>>(qkv, ows);

  // y = combine(ows) @ w_out^T + b_out — combine fused into A-staging,
  // same single-barrier dbuf pipeline as gemm1
  gemm2_pipe_kernel<<<dim3(264, 2), 256, 0, stream>>>(ows, woutb, b_out, y, 33792, 256, 256);
}